// Round 5
// baseline (880.128 us; speedup 1.0000x reference)
//
#include <hip/hip_runtime.h>
#include <hip/hip_bf16.h>
#include <hip/hip_fp16.h>

static constexpr int FDIM = 128;
static constexpr int NBKT = 1024;       // padded bucket count (bucket = dst>>7)

typedef _Float16 h8 __attribute__((ext_vector_type(8)));
typedef _Float16 h2 __attribute__((ext_vector_type(2)));
typedef float v4f __attribute__((ext_vector_type(4)));

// ================= norm / CSR build =================

__global__ __launch_bounds__(256) void k_zero_init(int* __restrict__ counts,
                                                   int* __restrict__ bucketCnt,
                                                   float* __restrict__ colsum,
                                                   float* __restrict__ colmax,
                                                   int n) {
    int i = blockIdx.x * 256 + threadIdx.x;
    if (i < n) counts[i] = 0;
    if (i < NBKT) bucketCnt[i] = 0;
    if (i < FDIM) { colsum[i] = 0.0f; colmax[i] = 0.0f; }
}

// per-node degree + coarse bucket histogram (LDS-aggregated), grid-stride
__global__ __launch_bounds__(256) void k_hist(const int* __restrict__ dst,
                                              int* __restrict__ counts,
                                              int* __restrict__ bucketCnt, int ne) {
    __shared__ int lb[NBKT];
    for (int j = threadIdx.x; j < NBKT; j += 256) lb[j] = 0;
    __syncthreads();
    int stride = gridDim.x * 256;
    for (int e = blockIdx.x * 256 + threadIdx.x; e < ne; e += stride) {
        int d = dst[e];
        atomicAdd(&counts[d], 1);
        atomicAdd(&lb[d >> 7], 1);
    }
    __syncthreads();
    for (int j = threadIdx.x; j < NBKT; j += 256)
        if (lb[j]) atomicAdd(&bucketCnt[j], lb[j]);
}

__global__ __launch_bounds__(256) void k_dinv(const int* __restrict__ counts,
                                              float* __restrict__ dinv, int n) {
    int i = blockIdx.x * 256 + threadIdx.x;
    if (i < n) dinv[i] = 1.0f / sqrtf(1.0f + (float)counts[i]);  // +1 self loop
}

// ---------- exclusive scan of per-node counts (3-pass), n <= 512*256 ----------

__global__ __launch_bounds__(256) void k_scan1(const int* __restrict__ counts,
                                               int* __restrict__ work,
                                               int* __restrict__ partials, int n) {
    __shared__ int tmp[256];
    int i = blockIdx.x * 256 + threadIdx.x;
    int v = (i < n) ? counts[i] : 0;
    tmp[threadIdx.x] = v;
    __syncthreads();
    for (int off = 1; off < 256; off <<= 1) {
        int t = (threadIdx.x >= off) ? tmp[threadIdx.x - off] : 0;
        __syncthreads();
        tmp[threadIdx.x] += t;
        __syncthreads();
    }
    if (i < n) work[i] = tmp[threadIdx.x] - v;           // exclusive
    if (threadIdx.x == 255) partials[blockIdx.x] = tmp[255];
}

__global__ __launch_bounds__(512) void k_scan2(int* __restrict__ partials, int nb) {
    __shared__ int tmp[512];
    int v = (threadIdx.x < nb) ? partials[threadIdx.x] : 0;
    tmp[threadIdx.x] = v;
    __syncthreads();
    for (int off = 1; off < 512; off <<= 1) {
        int t = (threadIdx.x >= off) ? tmp[threadIdx.x - off] : 0;
        __syncthreads();
        tmp[threadIdx.x] += t;
        __syncthreads();
    }
    if (threadIdx.x < nb) partials[threadIdx.x] = tmp[threadIdx.x] - v;  // exclusive
}

__global__ __launch_bounds__(256) void k_scan3(int* __restrict__ work,
                                               const int* __restrict__ partials, int n) {
    int i = blockIdx.x * 256 + threadIdx.x;
    if (i < n) work[i] += partials[blockIdx.x];
}

// ---------- bucket scan: bucketOff/bucketCur = exclusive scan of bucketCnt ----------

__global__ __launch_bounds__(1024) void k_scanB(const int* __restrict__ bucketCnt,
                                                int* __restrict__ bucketOff,
                                                int* __restrict__ bucketCur) {
    __shared__ int tmp[NBKT];
    int t = threadIdx.x;
    int v = bucketCnt[t];
    tmp[t] = v;
    __syncthreads();
    for (int off = 1; off < NBKT; off <<= 1) {
        int u = (t >= off) ? tmp[t - off] : 0;
        __syncthreads();
        tmp[t] += u;
        __syncthreads();
    }
    int excl = tmp[t] - v;
    bucketOff[t] = excl;
    bucketCur[t] = excl;
}

// ---------- pass B: bin edges into bucket-contiguous ebuf (8B packed) ----------

__global__ __launch_bounds__(256) void k_binfill(const int* __restrict__ src,
                                                 const int* __restrict__ dst,
                                                 int* __restrict__ bucketCur,
                                                 unsigned long long* __restrict__ ebuf,
                                                 int ne) {
    int stride = gridDim.x * 256;
    for (int e = blockIdx.x * 256 + threadIdx.x; e < ne; e += stride) {
        int s = src[e], d = dst[e];
        int pos = atomicAdd(&bucketCur[d >> 7], 1);
        ebuf[pos] = ((unsigned long long)(unsigned)d << 32) | (unsigned)s;
    }
}

// ---------- pass C: exact fill within bucket; LDS cursors, L2-hot csr window ----------

__global__ __launch_bounds__(256) void k_bucketfill(const unsigned long long* __restrict__ ebuf,
                                                    const int* __restrict__ bucketOff,
                                                    const int* __restrict__ bucketCur,
                                                    const int* __restrict__ work,
                                                    int* __restrict__ csr, int n) {
    __shared__ int cur[128];
    const int b = blockIdx.x;
    const int base = b << 7;
    if (threadIdx.x < 128 && base + threadIdx.x < n)
        cur[threadIdx.x] = work[base + threadIdx.x];
    __syncthreads();
    const int beg = bucketOff[b], end = bucketCur[b];
    for (int i = beg + threadIdx.x; i < end; i += 256) {
        unsigned long long p = ebuf[i];
        int d = (int)(p >> 32);
        int s = (int)(p & 0xffffffffu);
        int pos = atomicAdd(&cur[d & 127], 1);
        csr[pos] = s;
    }
}

// ---------- W transpose + fp16 cast: T[n][k] = (fp16) W[k][n] ----------

__global__ __launch_bounds__(256) void k_transW(const float* __restrict__ W1,
                                                const float* __restrict__ W2,
                                                _Float16* __restrict__ T1,
                                                _Float16* __restrict__ T2) {
    int b = blockIdx.x;                       // 0..127
    const float* W = (b < 64) ? W1 : W2;
    _Float16* T = (b < 64) ? T1 : T2;
    int idx = (b & 63) * 256 + threadIdx.x;   // 0..16383
    int k = idx >> 7, nn = idx & 127;
    T[nn * FDIM + k] = (_Float16)W[idx];
}

// ---------- MFMA GEMM: H(fp16) = X @ W  (M x 128 x 128) ----------

template <typename T>
__global__ __launch_bounds__(256) void k_gemm_f16(const T* __restrict__ X,
                                                  const _Float16* __restrict__ WT,
                                                  _Float16* __restrict__ H, int n) {
    __shared__ _Float16 sA[FDIM * FDIM];   // 32 KB
    __shared__ _Float16 sB[FDIM * FDIM];   // 32 KB
    const int t = threadIdx.x;
    const int lane = t & 63;
    const int w = t >> 6;
    const int rowhalf = w >> 1, colhalf = w & 1;

    for (int i = 0; i < 8; i++) {          // stage W^T once
        int f = i * 256 + t;
        int nn = f >> 4, g = f & 15;
        ((float4*)sB)[nn * 16 + ((g ^ nn) & 15)] = ((const float4*)WT)[f];
    }

    const int ntiles = (n + 127) >> 7;
    for (int tile = blockIdx.x; tile < ntiles; tile += gridDim.x) {
        const int R0 = tile << 7;
        __syncthreads();                    // frag readers done / sB staged
        for (int i = 0; i < 8; i++) {
            int f = i * 256 + t;
            int row = f >> 4, g = f & 15;
            int gr = min(R0 + row, n - 1);
            h8 val;
            if constexpr (sizeof(T) == 4) {
                const float4* xp = (const float4*)(X + (size_t)gr * FDIM + g * 8);
                float4 u0 = xp[0], u1 = xp[1];
                val[0] = (_Float16)u0.x; val[1] = (_Float16)u0.y;
                val[2] = (_Float16)u0.z; val[3] = (_Float16)u0.w;
                val[4] = (_Float16)u1.x; val[5] = (_Float16)u1.y;
                val[6] = (_Float16)u1.z; val[7] = (_Float16)u1.w;
            } else {
                val = ((const h8*)(X + (size_t)gr * FDIM))[g];
            }
            ((h8*)sA)[row * 16 + ((g ^ row) & 15)] = val;
        }
        __syncthreads();

        v4f acc[4][4];
#pragma unroll
        for (int rt = 0; rt < 4; rt++)
#pragma unroll
            for (int ct = 0; ct < 4; ct++)
                acc[rt][ct] = (v4f){0.f, 0.f, 0.f, 0.f};

#pragma unroll
        for (int s = 0; s < 4; s++) {
            const int g0 = s * 4 + (lane >> 4);
            h8 af[4], bf[4];
#pragma unroll
            for (int rt = 0; rt < 4; rt++) {
                int row = rowhalf * 64 + rt * 16 + (lane & 15);
                af[rt] = ((const h8*)sA)[row * 16 + ((g0 ^ row) & 15)];
            }
#pragma unroll
            for (int ct = 0; ct < 4; ct++) {
                int nn = colhalf * 64 + ct * 16 + (lane & 15);
                bf[ct] = ((const h8*)sB)[nn * 16 + ((g0 ^ nn) & 15)];
            }
#pragma unroll
            for (int rt = 0; rt < 4; rt++)
#pragma unroll
                for (int ct = 0; ct < 4; ct++)
                    acc[rt][ct] = __builtin_amdgcn_mfma_f32_16x16x32_f16(
                        af[rt], bf[ct], acc[rt][ct], 0, 0, 0);
        }

        // epilogue: C/D layout col = lane&15, row = (lane>>4)*4 + reg
        const int rb = R0 + rowhalf * 64 + (lane >> 4) * 4;
        const int cb = colhalf * 64 + (lane & 15);
#pragma unroll
        for (int rt = 0; rt < 4; rt++)
#pragma unroll
            for (int reg = 0; reg < 4; reg++) {
                int grow = rb + rt * 16 + reg;
                if (grow < n) {
                    _Float16* hp = H + (size_t)grow * FDIM + cb;
#pragma unroll
                    for (int ct = 0; ct < 4; ct++)
                        hp[ct * 16] = (_Float16)acc[rt][ct][reg];
                }
            }
    }
}

// ---------- gather aggregate (fp16 messages, fp32 accumulate) ----------
// work[] holds start offsets (pure exclusive scan); end = work[node+1] or ne.

__global__ __launch_bounds__(256) void k_aggregate(const int* __restrict__ work,
                                                   const int* __restrict__ csr,
                                                   const float* __restrict__ dinv,
                                                   const _Float16* __restrict__ hs,
                                                   const float* __restrict__ bias,
                                                   _Float16* __restrict__ out,
                                                   int n, int ne) {
    const int lane = threadIdx.x & 63;
    const int nwaves = gridDim.x * 4;
    int wid = (blockIdx.x * 256 + threadIdx.x) >> 6;
    const h2* hs2 = (const h2*)hs;
    const float2 bb = ((const float2*)bias)[lane];

    for (int node = wid; node < n; node += nwaves) {
        int beg = work[node];
        int end = (node + 1 < n) ? work[node + 1] : ne;
        float dd = dinv[node];
        h2 hv = hs2[(size_t)node * 64 + lane];
        float ax = dd * (float)hv[0];
        float ay = dd * (float)hv[1];
        for (int chunk = beg; chunk < end; chunk += 64) {
            int m = end - chunk; if (m > 64) m = 64;
            int myidx = (lane < m) ? csr[chunk + lane] : 0;
            for (int j = 0; j < m; j++) {
                int s = __shfl(myidx, j);
                float ws = dinv[s];
                h2 v = hs2[(size_t)s * 64 + lane];
                ax += ws * (float)v[0];
                ay += ws * (float)v[1];
            }
        }
        float ox = fmaxf(ax * dd + bb.x, 0.f);
        float oy = fmaxf(ay * dd + bb.y, 0.f);
        h2 o; o[0] = (_Float16)ox; o[1] = (_Float16)oy;
        ((h2*)out)[(size_t)node * 64 + lane] = o;
    }
}

// ---------- pools ----------

__global__ __launch_bounds__(256) void k_pool_h(const _Float16* __restrict__ X,
                                                float* __restrict__ colsum,
                                                float* __restrict__ colmax, int n) {
    __shared__ float ls[256], lm[256];
    int c = threadIdx.x & 127;
    int grp = threadIdx.x >> 7;
    float s = 0.f, m = 0.f;
    for (int r = blockIdx.x * 2 + grp; r < n; r += gridDim.x * 2) {
        float v = (float)X[(size_t)r * FDIM + c];
        s += v;
        m = fmaxf(m, v);
    }
    ls[threadIdx.x] = s;
    lm[threadIdx.x] = m;
    __syncthreads();
    if (threadIdx.x < 128) {
        s = ls[threadIdx.x] + ls[threadIdx.x + 128];
        m = fmaxf(lm[threadIdx.x], lm[threadIdx.x + 128]);
        unsafeAtomicAdd(&colsum[c], s);
        atomicMax((int*)colmax + c, __float_as_int(m));
    }
}

__global__ __launch_bounds__(256) void k_pool_f(const float* __restrict__ X,
                                                float* __restrict__ colsum,
                                                float* __restrict__ colmax, int n) {
    __shared__ float ls[256], lm[256];
    int c = threadIdx.x & 127;
    int grp = threadIdx.x >> 7;
    float s = 0.f, m = 0.f;
    for (int r = blockIdx.x * 2 + grp; r < n; r += gridDim.x * 2) {
        float v = X[(size_t)r * FDIM + c];
        s += v;
        m = fmaxf(m, v);
    }
    ls[threadIdx.x] = s;
    lm[threadIdx.x] = m;
    __syncthreads();
    if (threadIdx.x < 128) {
        s = ls[threadIdx.x] + ls[threadIdx.x + 128];
        m = fmaxf(lm[threadIdx.x], lm[threadIdx.x + 128]);
        unsafeAtomicAdd(&colsum[c], s);
        atomicMax((int*)colmax + c, __float_as_int(m));
    }
}

__global__ __launch_bounds__(256) void k_fc(const float* __restrict__ colsum,
                                            const float* __restrict__ colmax,
                                            const float* __restrict__ fcW,
                                            const float* __restrict__ fcb,
                                            float* __restrict__ out, float invN) {
    int o = threadIdx.x;
    float acc = fcb[o];
#pragma unroll 4
    for (int k = 0; k < FDIM; k++)
        acc += colsum[k] * invN * fcW[k * 256 + o];
#pragma unroll 4
    for (int k = 0; k < FDIM; k++)
        acc += colmax[k] * fcW[(FDIM + k) * 256 + o];
    out[o] = acc;
}

// ================= fallback (round-1 atomic scatter, fp32) =================

__global__ __launch_bounds__(256) void k_initF(float* deg, float* cs, float* cm, int n) {
    int i = blockIdx.x * 256 + threadIdx.x;
    if (i < n) deg[i] = 1.0f;
    if (i < FDIM) { cs[i] = 0.0f; cm[i] = 0.0f; }
}
__global__ __launch_bounds__(256) void k_degreeF(const int* dst, float* deg, int ne) {
    int i = blockIdx.x * 256 + threadIdx.x;
    if (i < ne) unsafeAtomicAdd(&deg[dst[i]], 1.0f);
}
__global__ __launch_bounds__(256) void k_rsqrtF(float* deg, int n) {
    int i = blockIdx.x * 256 + threadIdx.x;
    if (i < n) deg[i] = 1.0f / sqrtf(deg[i]);
}
__global__ __launch_bounds__(256) void k_selfinitF(const float* H, const float* dinv,
                                                   float* acc, int n) {
    int i = blockIdx.x * 256 + threadIdx.x;
    if (i >= n * 32) return;
    int row = i >> 5;
    float s = dinv[row]; s *= s;
    float4 v = ((const float4*)H)[i];
    v.x *= s; v.y *= s; v.z *= s; v.w *= s;
    ((float4*)acc)[i] = v;
}
__global__ __launch_bounds__(256) void k_scatterF(const int* src, const int* dst,
                                                  const float* dinv, const float* H,
                                                  float* acc, int ne) {
    int e = (blockIdx.x * 256 + threadIdx.x) >> 6;
    if (e >= ne) return;
    int lane = threadIdx.x & 63;
    int s = src[e], d = dst[e];
    float w = dinv[s] * dinv[d];
    float2 v = ((const float2*)(H + (size_t)s * FDIM))[lane];
    float* ap = acc + (size_t)d * FDIM + lane * 2;
    unsafeAtomicAdd(ap, v.x * w);
    unsafeAtomicAdd(ap + 1, v.y * w);
}
__global__ __launch_bounds__(256) void k_bias_reluF(float* acc, const float* b, int n) {
    int i = blockIdx.x * 256 + threadIdx.x;
    if (i >= n * 32) return;
    float4 bb = ((const float4*)b)[i & 31];
    float4 v = ((float4*)acc)[i];
    v.x = fmaxf(v.x + bb.x, 0.f);
    v.y = fmaxf(v.y + bb.y, 0.f);
    v.z = fmaxf(v.z + bb.z, 0.f);
    v.w = fmaxf(v.w + bb.w, 0.f);
    ((float4*)acc)[i] = v;
}
__global__ __launch_bounds__(256) void k_gemm128F(const float* X, const float* W,
                                                   float* H, int n) {
    __shared__ float sW[FDIM * FDIM];
    for (int i = threadIdx.x; i < FDIM * FDIM / 4; i += 256)
        ((float4*)sW)[i] = ((const float4*)W)[i];
    __syncthreads();
    const int c = threadIdx.x & 127;
    const int half = threadIdx.x >> 7;
    for (int base = blockIdx.x * 8; base < n; base += gridDim.x * 8) {
        const int r0 = base + half * 4;
        const float* xp0 = X + (size_t)min(r0 + 0, n - 1) * FDIM;
        const float* xp1 = X + (size_t)min(r0 + 1, n - 1) * FDIM;
        const float* xp2 = X + (size_t)min(r0 + 2, n - 1) * FDIM;
        const float* xp3 = X + (size_t)min(r0 + 3, n - 1) * FDIM;
        float a0 = 0.f, a1 = 0.f, a2 = 0.f, a3 = 0.f;
#pragma unroll 8
        for (int k = 0; k < FDIM; k += 4) {
            float w0 = sW[(k + 0) * FDIM + c];
            float w1 = sW[(k + 1) * FDIM + c];
            float w2 = sW[(k + 2) * FDIM + c];
            float w3 = sW[(k + 3) * FDIM + c];
            float4 x0 = *(const float4*)(xp0 + k);
            float4 x1 = *(const float4*)(xp1 + k);
            float4 x2 = *(const float4*)(xp2 + k);
            float4 x3 = *(const float4*)(xp3 + k);
            a0 += x0.x * w0 + x0.y * w1 + x0.z * w2 + x0.w * w3;
            a1 += x1.x * w0 + x1.y * w1 + x1.z * w2 + x1.w * w3;
            a2 += x2.x * w0 + x2.y * w1 + x2.z * w2 + x2.w * w3;
            a3 += x3.x * w0 + x3.y * w1 + x3.z * w2 + x3.w * w3;
        }
        if (r0 + 0 < n) H[(size_t)(r0 + 0) * FDIM + c] = a0;
        if (r0 + 1 < n) H[(size_t)(r0 + 1) * FDIM + c] = a1;
        if (r0 + 2 < n) H[(size_t)(r0 + 2) * FDIM + c] = a2;
        if (r0 + 3 < n) H[(size_t)(r0 + 3) * FDIM + c] = a3;
    }
}

// ================= launch =================

extern "C" void kernel_launch(void* const* d_in, const int* in_sizes, int n_in,
                              void* d_out, int out_size, void* d_ws, size_t ws_size,
                              hipStream_t stream) {
    const float* X   = (const float*)d_in[0];
    const int*   ei  = (const int*)d_in[1];
    const float* W1  = (const float*)d_in[2];
    const float* b1  = (const float*)d_in[3];
    const float* W2  = (const float*)d_in[4];
    const float* b2  = (const float*)d_in[5];
    const float* fcW = (const float*)d_in[6];
    const float* fcb = (const float*)d_in[7];
    float* out = (float*)d_out;

    const int n  = in_sizes[0] / FDIM;    // 100000
    const int ne = in_sizes[1] / 2;       // 1600000
    const int* src = ei;
    const int* dst = ei + ne;

    const int gN = (n + 255) / 256;
    const int nbkt = (n + 127) >> 7;      // real bucket count (<= NBKT)

    // workspace: ebuf(8B) first for alignment, then fp16 bufs, then fp32/int
    size_t need = (size_t)ne * 8 + (size_t)n * FDIM * 2 * 2 + 2 * FDIM * FDIM * 2 +
                  ((size_t)n + 2 * FDIM) * 4 +
                  ((size_t)n * 2 + 512 + 3 * NBKT + ne) * 4;

    if (ws_size >= need && gN <= 512 && nbkt <= NBKT) {
        unsigned long long* ebuf = (unsigned long long*)d_ws;
        _Float16* h    = (_Float16*)(ebuf + ne);
        _Float16* xbuf = h + (size_t)n * FDIM;
        _Float16* w1t  = xbuf + (size_t)n * FDIM;
        _Float16* w2t  = w1t + FDIM * FDIM;
        float* dinv    = (float*)(w2t + FDIM * FDIM);
        float* colsum  = dinv + n;
        float* colmax  = colsum + FDIM;
        int* counts    = (int*)(colmax + FDIM);
        int* work      = counts + n;
        int* partials  = work + n;
        int* bucketCnt = partials + 512;
        int* bucketOff = bucketCnt + NBKT;
        int* bucketCur = bucketOff + NBKT;
        int* csr       = bucketCur + NBKT;

        k_zero_init<<<gN, 256, 0, stream>>>(counts, bucketCnt, colsum, colmax, n);
        k_hist<<<1024, 256, 0, stream>>>(dst, counts, bucketCnt, ne);
        k_dinv<<<gN, 256, 0, stream>>>(counts, dinv, n);
        k_scan1<<<gN, 256, 0, stream>>>(counts, work, partials, n);
        k_scan2<<<1, 512, 0, stream>>>(partials, gN);
        k_scan3<<<gN, 256, 0, stream>>>(work, partials, n);
        k_scanB<<<1, NBKT, 0, stream>>>(bucketCnt, bucketOff, bucketCur);
        k_binfill<<<1024, 256, 0, stream>>>(src, dst, bucketCur, ebuf, ne);
        k_bucketfill<<<nbkt, 256, 0, stream>>>(ebuf, bucketOff, bucketCur, work, csr, n);
        k_transW<<<128, 256, 0, stream>>>(W1, W2, w1t, w2t);

        k_gemm_f16<float><<<512, 256, 0, stream>>>(X, w1t, h, n);
        k_aggregate<<<2048, 256, 0, stream>>>(work, csr, dinv, h, b1, xbuf, n, ne);
        k_gemm_f16<_Float16><<<512, 256, 0, stream>>>(xbuf, w2t, h, n);
        k_aggregate<<<2048, 256, 0, stream>>>(work, csr, dinv, h, b2, xbuf, n, ne);

        k_pool_h<<<1024, 256, 0, stream>>>(xbuf, colsum, colmax, n);
        k_fc<<<1, 256, 0, stream>>>(colsum, colmax, fcW, fcb, out, 1.0f / (float)n);
    } else {
        float* h      = (float*)d_ws;
        float* acc    = h + (size_t)n * FDIM;
        float* dinv   = acc + (size_t)n * FDIM;
        float* colsum = dinv + n;
        float* colmax = colsum + FDIM;
        const int gV = (n * 32 + 255) / 256;
        const int gS = (int)(((long long)ne * 64 + 255) / 256);
        const int gE = (ne + 255) / 256;

        k_initF<<<gN, 256, 0, stream>>>(dinv, colsum, colmax, n);
        k_degreeF<<<gE, 256, 0, stream>>>(dst, dinv, ne);
        k_rsqrtF<<<gN, 256, 0, stream>>>(dinv, n);

        k_gemm128F<<<1024, 256, 0, stream>>>(X, W1, h, n);
        k_selfinitF<<<gV, 256, 0, stream>>>(h, dinv, acc, n);
        k_scatterF<<<gS, 256, 0, stream>>>(src, dst, dinv, h, acc, ne);
        k_bias_reluF<<<gV, 256, 0, stream>>>(acc, b1, n);

        k_gemm128F<<<1024, 256, 0, stream>>>(acc, W2, h, n);
        k_selfinitF<<<gV, 256, 0, stream>>>(h, dinv, acc, n);
        k_scatterF<<<gS, 256, 0, stream>>>(src, dst, dinv, h, acc, ne);
        k_bias_reluF<<<gV, 256, 0, stream>>>(acc, b2, n);

        k_pool_f<<<1024, 256, 0, stream>>>(acc, colsum, colmax, n);
        k_fc<<<1, 256, 0, stream>>>(colsum, colmax, fcW, fcb, out, 1.0f / (float)n);
    }
}

// Round 6
// 512.236 us; speedup vs baseline: 1.7182x; 1.7182x over previous
//
#include <hip/hip_runtime.h>
#include <hip/hip_bf16.h>
#include <hip/hip_fp16.h>

static constexpr int FDIM = 128;
static constexpr int NBKT = 1024;       // padded bucket count (bucket = dst>>7)

typedef _Float16 h8 __attribute__((ext_vector_type(8)));
typedef _Float16 h2 __attribute__((ext_vector_type(2)));
typedef float v4f __attribute__((ext_vector_type(4)));

// ================= norm / CSR build =================

__global__ __launch_bounds__(256) void k_zero_init(int* __restrict__ counts,
                                                   float* __restrict__ colsum,
                                                   float* __restrict__ colmax,
                                                   int n) {
    int i = blockIdx.x * 256 + threadIdx.x;
    if (i < n) counts[i] = 0;
    if (i < FDIM) { colsum[i] = 0.0f; colmax[i] = 0.0f; }
}

__global__ __launch_bounds__(256) void k_hist(const int* __restrict__ dst,
                                              int* __restrict__ counts, int ne) {
    int i = blockIdx.x * 256 + threadIdx.x;
    if (i < ne) atomicAdd(&counts[dst[i]], 1);
}

__global__ __launch_bounds__(256) void k_dinv(const int* __restrict__ counts,
                                              float* __restrict__ dinv, int n) {
    int i = blockIdx.x * 256 + threadIdx.x;
    if (i < n) dinv[i] = 1.0f / sqrtf(1.0f + (float)counts[i]);  // +1 self loop
}

// ---------- exclusive scan of per-node counts (3-pass), n <= 512*256 ----------

__global__ __launch_bounds__(256) void k_scan1(const int* __restrict__ counts,
                                               int* __restrict__ work,
                                               int* __restrict__ partials, int n) {
    __shared__ int tmp[256];
    int i = blockIdx.x * 256 + threadIdx.x;
    int v = (i < n) ? counts[i] : 0;
    tmp[threadIdx.x] = v;
    __syncthreads();
    for (int off = 1; off < 256; off <<= 1) {
        int t = (threadIdx.x >= off) ? tmp[threadIdx.x - off] : 0;
        __syncthreads();
        tmp[threadIdx.x] += t;
        __syncthreads();
    }
    if (i < n) work[i] = tmp[threadIdx.x] - v;           // exclusive
    if (threadIdx.x == 255) partials[blockIdx.x] = tmp[255];
}

__global__ __launch_bounds__(512) void k_scan2(int* __restrict__ partials, int nb) {
    __shared__ int tmp[512];
    int v = (threadIdx.x < nb) ? partials[threadIdx.x] : 0;
    tmp[threadIdx.x] = v;
    __syncthreads();
    for (int off = 1; off < 512; off <<= 1) {
        int t = (threadIdx.x >= off) ? tmp[threadIdx.x - off] : 0;
        __syncthreads();
        tmp[threadIdx.x] += t;
        __syncthreads();
    }
    if (threadIdx.x < nb) partials[threadIdx.x] = tmp[threadIdx.x] - v;  // exclusive
}

__global__ __launch_bounds__(256) void k_scan3(int* __restrict__ work,
                                               const int* __restrict__ partials, int n) {
    int i = blockIdx.x * 256 + threadIdx.x;
    if (i < n) work[i] += partials[blockIdx.x];
}

// ---------- seed bucket cursors from the node scan: bucketCur[b] = work[b*128] ----------

__global__ __launch_bounds__(1024) void k_bcur(const int* __restrict__ work,
                                               int* __restrict__ bucketCur, int n) {
    int b = threadIdx.x;
    int node = b << 7;
    bucketCur[b] = (node < n) ? work[node] : 0;
}

// ---------- pass B: bin edges into bucket-contiguous ebuf (8B packed) ----------
// Per-block aggregation kills cursor contention: LDS histogram -> one global
// atomicAdd per touched bucket per block (range reservation) -> contiguous
// run writes. 4096 edges/block.

__global__ __launch_bounds__(256) void k_binfill(const int* __restrict__ src,
                                                 const int* __restrict__ dst,
                                                 int* __restrict__ bucketCur,
                                                 unsigned long long* __restrict__ ebuf,
                                                 int ne) {
    __shared__ int lcnt[NBKT];    // phase1: counts, phase3: local cursor
    __shared__ int lbase[NBKT];   // reserved global base per bucket
    const int e0 = blockIdx.x * 4096;
    for (int j = threadIdx.x; j < NBKT; j += 256) lcnt[j] = 0;
    __syncthreads();

    int dcache[16];
#pragma unroll
    for (int i = 0; i < 16; i++) {
        int e = e0 + i * 256 + threadIdx.x;
        int d = (e < ne) ? dst[e] : -1;
        dcache[i] = d;
        if (d >= 0) atomicAdd(&lcnt[d >> 7], 1);
    }
    __syncthreads();

    for (int j = threadIdx.x; j < NBKT; j += 256) {
        int c = lcnt[j];
        lbase[j] = c ? atomicAdd(&bucketCur[j], c) : 0;
        lcnt[j] = 0;      // safe: only this thread touches index j in this phase
    }
    __syncthreads();

#pragma unroll
    for (int i = 0; i < 16; i++) {
        int e = e0 + i * 256 + threadIdx.x;
        if (e < ne) {
            int d = dcache[i];
            int s = src[e];
            int b = d >> 7;
            int lp = atomicAdd(&lcnt[b], 1);
            ebuf[lbase[b] + lp] =
                ((unsigned long long)(unsigned)d << 32) | (unsigned)s;
        }
    }
}

// ---------- pass C: exact fill within bucket; LDS cursors, L2-hot csr window ----------
// bucket b's range in ebuf/csr index space is [work[b*128], work[(b+1)*128]).

__global__ __launch_bounds__(256) void k_bucketfill(const unsigned long long* __restrict__ ebuf,
                                                    const int* __restrict__ work,
                                                    int* __restrict__ csr,
                                                    int n, int ne) {
    __shared__ int cur[128];
    const int b = blockIdx.x;
    const int base = b << 7;
    const int nodes = min(128, n - base);
    if (threadIdx.x < nodes) cur[threadIdx.x] = work[base + threadIdx.x];
    __syncthreads();
    const int beg = work[base];
    const int endn = base + 128;
    const int end = (endn < n) ? work[endn] : ne;
    for (int i = beg + threadIdx.x; i < end; i += 256) {
        unsigned long long p = ebuf[i];
        int d = (int)(p >> 32);
        int s = (int)(p & 0xffffffffu);
        int pos = atomicAdd(&cur[d & 127], 1);
        csr[pos] = s;
    }
}

// ---------- W transpose + fp16 cast: T[n][k] = (fp16) W[k][n] ----------

__global__ __launch_bounds__(256) void k_transW(const float* __restrict__ W1,
                                                const float* __restrict__ W2,
                                                _Float16* __restrict__ T1,
                                                _Float16* __restrict__ T2) {
    int b = blockIdx.x;                       // 0..127
    const float* W = (b < 64) ? W1 : W2;
    _Float16* T = (b < 64) ? T1 : T2;
    int idx = (b & 63) * 256 + threadIdx.x;   // 0..16383
    int k = idx >> 7, nn = idx & 127;
    T[nn * FDIM + k] = (_Float16)W[idx];
}

// ---------- MFMA GEMM: H(fp16) = X @ W  (M x 128 x 128) ----------

template <typename T>
__global__ __launch_bounds__(256) void k_gemm_f16(const T* __restrict__ X,
                                                  const _Float16* __restrict__ WT,
                                                  _Float16* __restrict__ H, int n) {
    __shared__ _Float16 sA[FDIM * FDIM];   // 32 KB
    __shared__ _Float16 sB[FDIM * FDIM];   // 32 KB
    const int t = threadIdx.x;
    const int lane = t & 63;
    const int w = t >> 6;
    const int rowhalf = w >> 1, colhalf = w & 1;

    for (int i = 0; i < 8; i++) {          // stage W^T once
        int f = i * 256 + t;
        int nn = f >> 4, g = f & 15;
        ((float4*)sB)[nn * 16 + ((g ^ nn) & 15)] = ((const float4*)WT)[f];
    }

    const int ntiles = (n + 127) >> 7;
    for (int tile = blockIdx.x; tile < ntiles; tile += gridDim.x) {
        const int R0 = tile << 7;
        __syncthreads();                    // frag readers done / sB staged
        for (int i = 0; i < 8; i++) {
            int f = i * 256 + t;
            int row = f >> 4, g = f & 15;
            int gr = min(R0 + row, n - 1);
            h8 val;
            if constexpr (sizeof(T) == 4) {
                const float4* xp = (const float4*)(X + (size_t)gr * FDIM + g * 8);
                float4 u0 = xp[0], u1 = xp[1];
                val[0] = (_Float16)u0.x; val[1] = (_Float16)u0.y;
                val[2] = (_Float16)u0.z; val[3] = (_Float16)u0.w;
                val[4] = (_Float16)u1.x; val[5] = (_Float16)u1.y;
                val[6] = (_Float16)u1.z; val[7] = (_Float16)u1.w;
            } else {
                val = ((const h8*)(X + (size_t)gr * FDIM))[g];
            }
            ((h8*)sA)[row * 16 + ((g ^ row) & 15)] = val;
        }
        __syncthreads();

        v4f acc[4][4];
#pragma unroll
        for (int rt = 0; rt < 4; rt++)
#pragma unroll
            for (int ct = 0; ct < 4; ct++)
                acc[rt][ct] = (v4f){0.f, 0.f, 0.f, 0.f};

#pragma unroll
        for (int s = 0; s < 4; s++) {
            const int g0 = s * 4 + (lane >> 4);
            h8 af[4], bf[4];
#pragma unroll
            for (int rt = 0; rt < 4; rt++) {
                int row = rowhalf * 64 + rt * 16 + (lane & 15);
                af[rt] = ((const h8*)sA)[row * 16 + ((g0 ^ row) & 15)];
            }
#pragma unroll
            for (int ct = 0; ct < 4; ct++) {
                int nn = colhalf * 64 + ct * 16 + (lane & 15);
                bf[ct] = ((const h8*)sB)[nn * 16 + ((g0 ^ nn) & 15)];
            }
#pragma unroll
            for (int rt = 0; rt < 4; rt++)
#pragma unroll
                for (int ct = 0; ct < 4; ct++)
                    acc[rt][ct] = __builtin_amdgcn_mfma_f32_16x16x32_f16(
                        af[rt], bf[ct], acc[rt][ct], 0, 0, 0);
        }

        // epilogue: C/D layout col = lane&15, row = (lane>>4)*4 + reg
        const int rb = R0 + rowhalf * 64 + (lane >> 4) * 4;
        const int cb = colhalf * 64 + (lane & 15);
#pragma unroll
        for (int rt = 0; rt < 4; rt++)
#pragma unroll
            for (int reg = 0; reg < 4; reg++) {
                int grow = rb + rt * 16 + reg;
                if (grow < n) {
                    _Float16* hp = H + (size_t)grow * FDIM + cb;
#pragma unroll
                    for (int ct = 0; ct < 4; ct++)
                        hp[ct * 16] = (_Float16)acc[rt][ct][reg];
                }
            }
    }
}

// ---------- gather aggregate (fp16 messages, fp32 accumulate) ----------
// work[] holds start offsets (pure exclusive scan); end = work[node+1] or ne.

__global__ __launch_bounds__(256) void k_aggregate(const int* __restrict__ work,
                                                   const int* __restrict__ csr,
                                                   const float* __restrict__ dinv,
                                                   const _Float16* __restrict__ hs,
                                                   const float* __restrict__ bias,
                                                   _Float16* __restrict__ out,
                                                   int n, int ne) {
    const int lane = threadIdx.x & 63;
    const int nwaves = gridDim.x * 4;
    int wid = (blockIdx.x * 256 + threadIdx.x) >> 6;
    const h2* hs2 = (const h2*)hs;
    const float2 bb = ((const float2*)bias)[lane];

    for (int node = wid; node < n; node += nwaves) {
        int beg = work[node];
        int end = (node + 1 < n) ? work[node + 1] : ne;
        float dd = dinv[node];
        h2 hv = hs2[(size_t)node * 64 + lane];
        float ax = dd * (float)hv[0];
        float ay = dd * (float)hv[1];
        for (int chunk = beg; chunk < end; chunk += 64) {
            int m = end - chunk; if (m > 64) m = 64;
            int myidx = (lane < m) ? csr[chunk + lane] : 0;
            for (int j = 0; j < m; j++) {
                int s = __shfl(myidx, j);
                float ws = dinv[s];
                h2 v = hs2[(size_t)s * 64 + lane];
                ax += ws * (float)v[0];
                ay += ws * (float)v[1];
            }
        }
        float ox = fmaxf(ax * dd + bb.x, 0.f);
        float oy = fmaxf(ay * dd + bb.y, 0.f);
        h2 o; o[0] = (_Float16)ox; o[1] = (_Float16)oy;
        ((h2*)out)[(size_t)node * 64 + lane] = o;
    }
}

// ---------- pools ----------

__global__ __launch_bounds__(256) void k_pool_h(const _Float16* __restrict__ X,
                                                float* __restrict__ colsum,
                                                float* __restrict__ colmax, int n) {
    __shared__ float ls[256], lm[256];
    int c = threadIdx.x & 127;
    int grp = threadIdx.x >> 7;
    float s = 0.f, m = 0.f;
    for (int r = blockIdx.x * 2 + grp; r < n; r += gridDim.x * 2) {
        float v = (float)X[(size_t)r * FDIM + c];
        s += v;
        m = fmaxf(m, v);
    }
    ls[threadIdx.x] = s;
    lm[threadIdx.x] = m;
    __syncthreads();
    if (threadIdx.x < 128) {
        s = ls[threadIdx.x] + ls[threadIdx.x + 128];
        m = fmaxf(lm[threadIdx.x], lm[threadIdx.x + 128]);
        unsafeAtomicAdd(&colsum[c], s);
        atomicMax((int*)colmax + c, __float_as_int(m));
    }
}

__global__ __launch_bounds__(256) void k_pool_f(const float* __restrict__ X,
                                                float* __restrict__ colsum,
                                                float* __restrict__ colmax, int n) {
    __shared__ float ls[256], lm[256];
    int c = threadIdx.x & 127;
    int grp = threadIdx.x >> 7;
    float s = 0.f, m = 0.f;
    for (int r = blockIdx.x * 2 + grp; r < n; r += gridDim.x * 2) {
        float v = X[(size_t)r * FDIM + c];
        s += v;
        m = fmaxf(m, v);
    }
    ls[threadIdx.x] = s;
    lm[threadIdx.x] = m;
    __syncthreads();
    if (threadIdx.x < 128) {
        s = ls[threadIdx.x] + ls[threadIdx.x + 128];
        m = fmaxf(lm[threadIdx.x], lm[threadIdx.x + 128]);
        unsafeAtomicAdd(&colsum[c], s);
        atomicMax((int*)colmax + c, __float_as_int(m));
    }
}

__global__ __launch_bounds__(256) void k_fc(const float* __restrict__ colsum,
                                            const float* __restrict__ colmax,
                                            const float* __restrict__ fcW,
                                            const float* __restrict__ fcb,
                                            float* __restrict__ out, float invN) {
    int o = threadIdx.x;
    float acc = fcb[o];
#pragma unroll 4
    for (int k = 0; k < FDIM; k++)
        acc += colsum[k] * invN * fcW[k * 256 + o];
#pragma unroll 4
    for (int k = 0; k < FDIM; k++)
        acc += colmax[k] * fcW[(FDIM + k) * 256 + o];
    out[o] = acc;
}

// ================= fallback (round-1 atomic scatter, fp32) =================

__global__ __launch_bounds__(256) void k_initF(float* deg, float* cs, float* cm, int n) {
    int i = blockIdx.x * 256 + threadIdx.x;
    if (i < n) deg[i] = 1.0f;
    if (i < FDIM) { cs[i] = 0.0f; cm[i] = 0.0f; }
}
__global__ __launch_bounds__(256) void k_degreeF(const int* dst, float* deg, int ne) {
    int i = blockIdx.x * 256 + threadIdx.x;
    if (i < ne) unsafeAtomicAdd(&deg[dst[i]], 1.0f);
}
__global__ __launch_bounds__(256) void k_rsqrtF(float* deg, int n) {
    int i = blockIdx.x * 256 + threadIdx.x;
    if (i < n) deg[i] = 1.0f / sqrtf(deg[i]);
}
__global__ __launch_bounds__(256) void k_selfinitF(const float* H, const float* dinv,
                                                   float* acc, int n) {
    int i = blockIdx.x * 256 + threadIdx.x;
    if (i >= n * 32) return;
    int row = i >> 5;
    float s = dinv[row]; s *= s;
    float4 v = ((const float4*)H)[i];
    v.x *= s; v.y *= s; v.z *= s; v.w *= s;
    ((float4*)acc)[i] = v;
}
__global__ __launch_bounds__(256) void k_scatterF(const int* src, const int* dst,
                                                  const float* dinv, const float* H,
                                                  float* acc, int ne) {
    int e = (blockIdx.x * 256 + threadIdx.x) >> 6;
    if (e >= ne) return;
    int lane = threadIdx.x & 63;
    int s = src[e], d = dst[e];
    float w = dinv[s] * dinv[d];
    float2 v = ((const float2*)(H + (size_t)s * FDIM))[lane];
    float* ap = acc + (size_t)d * FDIM + lane * 2;
    unsafeAtomicAdd(ap, v.x * w);
    unsafeAtomicAdd(ap + 1, v.y * w);
}
__global__ __launch_bounds__(256) void k_bias_reluF(float* acc, const float* b, int n) {
    int i = blockIdx.x * 256 + threadIdx.x;
    if (i >= n * 32) return;
    float4 bb = ((const float4*)b)[i & 31];
    float4 v = ((float4*)acc)[i];
    v.x = fmaxf(v.x + bb.x, 0.f);
    v.y = fmaxf(v.y + bb.y, 0.f);
    v.z = fmaxf(v.z + bb.z, 0.f);
    v.w = fmaxf(v.w + bb.w, 0.f);
    ((float4*)acc)[i] = v;
}
__global__ __launch_bounds__(256) void k_gemm128F(const float* X, const float* W,
                                                   float* H, int n) {
    __shared__ float sW[FDIM * FDIM];
    for (int i = threadIdx.x; i < FDIM * FDIM / 4; i += 256)
        ((float4*)sW)[i] = ((const float4*)W)[i];
    __syncthreads();
    const int c = threadIdx.x & 127;
    const int half = threadIdx.x >> 7;
    for (int base = blockIdx.x * 8; base < n; base += gridDim.x * 8) {
        const int r0 = base + half * 4;
        const float* xp0 = X + (size_t)min(r0 + 0, n - 1) * FDIM;
        const float* xp1 = X + (size_t)min(r0 + 1, n - 1) * FDIM;
        const float* xp2 = X + (size_t)min(r0 + 2, n - 1) * FDIM;
        const float* xp3 = X + (size_t)min(r0 + 3, n - 1) * FDIM;
        float a0 = 0.f, a1 = 0.f, a2 = 0.f, a3 = 0.f;
#pragma unroll 8
        for (int k = 0; k < FDIM; k += 4) {
            float w0 = sW[(k + 0) * FDIM + c];
            float w1 = sW[(k + 1) * FDIM + c];
            float w2 = sW[(k + 2) * FDIM + c];
            float w3 = sW[(k + 3) * FDIM + c];
            float4 x0 = *(const float4*)(xp0 + k);
            float4 x1 = *(const float4*)(xp1 + k);
            float4 x2 = *(const float4*)(xp2 + k);
            float4 x3 = *(const float4*)(xp3 + k);
            a0 += x0.x * w0 + x0.y * w1 + x0.z * w2 + x0.w * w3;
            a1 += x1.x * w0 + x1.y * w1 + x1.z * w2 + x1.w * w3;
            a2 += x2.x * w0 + x2.y * w1 + x2.z * w2 + x2.w * w3;
            a3 += x3.x * w0 + x3.y * w1 + x3.z * w2 + x3.w * w3;
        }
        if (r0 + 0 < n) H[(size_t)(r0 + 0) * FDIM + c] = a0;
        if (r0 + 1 < n) H[(size_t)(r0 + 1) * FDIM + c] = a1;
        if (r0 + 2 < n) H[(size_t)(r0 + 2) * FDIM + c] = a2;
        if (r0 + 3 < n) H[(size_t)(r0 + 3) * FDIM + c] = a3;
    }
}

// ================= launch =================

extern "C" void kernel_launch(void* const* d_in, const int* in_sizes, int n_in,
                              void* d_out, int out_size, void* d_ws, size_t ws_size,
                              hipStream_t stream) {
    const float* X   = (const float*)d_in[0];
    const int*   ei  = (const int*)d_in[1];
    const float* W1  = (const float*)d_in[2];
    const float* b1  = (const float*)d_in[3];
    const float* W2  = (const float*)d_in[4];
    const float* b2  = (const float*)d_in[5];
    const float* fcW = (const float*)d_in[6];
    const float* fcb = (const float*)d_in[7];
    float* out = (float*)d_out;

    const int n  = in_sizes[0] / FDIM;    // 100000
    const int ne = in_sizes[1] / 2;       // 1600000
    const int* src = ei;
    const int* dst = ei + ne;

    const int gN = (n + 255) / 256;
    const int gE = (ne + 255) / 256;
    const int nbkt = (n + 127) >> 7;      // real bucket count (<= NBKT)
    const int gB = (ne + 4095) / 4096;    // binfill blocks

    // workspace: ebuf(8B) first for alignment, then fp16 bufs, then fp32/int
    size_t need = (size_t)ne * 8 + (size_t)n * FDIM * 2 * 2 + 2 * FDIM * FDIM * 2 +
                  ((size_t)n + 2 * FDIM) * 4 +
                  ((size_t)n * 2 + 512 + NBKT + ne) * 4;

    if (ws_size >= need && gN <= 512 && nbkt <= NBKT) {
        unsigned long long* ebuf = (unsigned long long*)d_ws;
        _Float16* h    = (_Float16*)(ebuf + ne);
        _Float16* xbuf = h + (size_t)n * FDIM;
        _Float16* w1t  = xbuf + (size_t)n * FDIM;
        _Float16* w2t  = w1t + FDIM * FDIM;
        float* dinv    = (float*)(w2t + FDIM * FDIM);
        float* colsum  = dinv + n;
        float* colmax  = colsum + FDIM;
        int* counts    = (int*)(colmax + FDIM);
        int* work      = counts + n;
        int* partials  = work + n;
        int* bucketCur = partials + 512;
        int* csr       = bucketCur + NBKT;

        k_zero_init<<<gN, 256, 0, stream>>>(counts, colsum, colmax, n);
        k_hist<<<gE, 256, 0, stream>>>(dst, counts, ne);
        k_dinv<<<gN, 256, 0, stream>>>(counts, dinv, n);
        k_scan1<<<gN, 256, 0, stream>>>(counts, work, partials, n);
        k_scan2<<<1, 512, 0, stream>>>(partials, gN);
        k_scan3<<<gN, 256, 0, stream>>>(work, partials, n);
        k_bcur<<<1, NBKT, 0, stream>>>(work, bucketCur, n);
        k_binfill<<<gB, 256, 0, stream>>>(src, dst, bucketCur, ebuf, ne);
        k_bucketfill<<<nbkt, 256, 0, stream>>>(ebuf, work, csr, n, ne);
        k_transW<<<128, 256, 0, stream>>>(W1, W2, w1t, w2t);

        k_gemm_f16<float><<<512, 256, 0, stream>>>(X, w1t, h, n);
        k_aggregate<<<2048, 256, 0, stream>>>(work, csr, dinv, h, b1, xbuf, n, ne);
        k_gemm_f16<_Float16><<<512, 256, 0, stream>>>(xbuf, w2t, h, n);
        k_aggregate<<<2048, 256, 0, stream>>>(work, csr, dinv, h, b2, xbuf, n, ne);

        k_pool_h<<<1024, 256, 0, stream>>>(xbuf, colsum, colmax, n);
        k_fc<<<1, 256, 0, stream>>>(colsum, colmax, fcW, fcb, out, 1.0f / (float)n);
    } else {
        float* h      = (float*)d_ws;
        float* acc    = h + (size_t)n * FDIM;
        float* dinv   = acc + (size_t)n * FDIM;
        float* colsum = dinv + n;
        float* colmax = colsum + FDIM;
        const int gV = (n * 32 + 255) / 256;
        const int gS = (int)(((long long)ne * 64 + 255) / 256);

        k_initF<<<gN, 256, 0, stream>>>(dinv, colsum, colmax, n);
        k_degreeF<<<gE, 256, 0, stream>>>(dst, dinv, ne);
        k_rsqrtF<<<gN, 256, 0, stream>>>(dinv, n);

        k_gemm128F<<<1024, 256, 0, stream>>>(X, W1, h, n);
        k_selfinitF<<<gV, 256, 0, stream>>>(h, dinv, acc, n);
        k_scatterF<<<gS, 256, 0, stream>>>(src, dst, dinv, h, acc, ne);
        k_bias_reluF<<<gV, 256, 0, stream>>>(acc, b1, n);

        k_gemm128F<<<1024, 256, 0, stream>>>(acc, W2, h, n);
        k_selfinitF<<<gV, 256, 0, stream>>>(h, dinv, acc, n);
        k_scatterF<<<gS, 256, 0, stream>>>(src, dst, dinv, h, acc, ne);
        k_bias_reluF<<<gV, 256, 0, stream>>>(acc, b2, n);

        k_pool_f<<<1024, 256, 0, stream>>>(acc, colsum, colmax, n);
        k_fc<<<1, 256, 0, stream>>>(colsum, colmax, fcW, fcb, out, 1.0f / (float)n);
    }
}

// Round 7
// 437.526 us; speedup vs baseline: 2.0116x; 1.1708x over previous
//
#include <hip/hip_runtime.h>
#include <hip/hip_bf16.h>
#include <hip/hip_fp16.h>

static constexpr int FDIM = 128;
static constexpr int NBKT = 1024;       // padded bucket count (bucket = dst>>7)

typedef _Float16 h8 __attribute__((ext_vector_type(8)));
typedef _Float16 h2 __attribute__((ext_vector_type(2)));
typedef float v4f __attribute__((ext_vector_type(4)));

// ================= norm / CSR build =================

__global__ __launch_bounds__(256) void k_zero_init(int* __restrict__ counts,
                                                   float* __restrict__ colsum,
                                                   float* __restrict__ colmax,
                                                   int n) {
    int i = blockIdx.x * 256 + threadIdx.x;
    if (i < n) counts[i] = 0;
    if (i < FDIM) { colsum[i] = 0.0f; colmax[i] = 0.0f; }
}

__global__ __launch_bounds__(256) void k_hist(const int* __restrict__ dst,
                                              int* __restrict__ counts, int ne) {
    int i = blockIdx.x * 256 + threadIdx.x;
    if (i < ne) atomicAdd(&counts[dst[i]], 1);
}

__global__ __launch_bounds__(256) void k_dinv(const int* __restrict__ counts,
                                              float* __restrict__ dinv, int n) {
    int i = blockIdx.x * 256 + threadIdx.x;
    if (i < n) dinv[i] = 1.0f / sqrtf(1.0f + (float)counts[i]);  // +1 self loop
}

// ---------- exclusive scan of per-node counts (3-pass), n <= 512*256 ----------

__global__ __launch_bounds__(256) void k_scan1(const int* __restrict__ counts,
                                               int* __restrict__ work,
                                               int* __restrict__ partials, int n) {
    __shared__ int tmp[256];
    int i = blockIdx.x * 256 + threadIdx.x;
    int v = (i < n) ? counts[i] : 0;
    tmp[threadIdx.x] = v;
    __syncthreads();
    for (int off = 1; off < 256; off <<= 1) {
        int t = (threadIdx.x >= off) ? tmp[threadIdx.x - off] : 0;
        __syncthreads();
        tmp[threadIdx.x] += t;
        __syncthreads();
    }
    if (i < n) work[i] = tmp[threadIdx.x] - v;           // exclusive
    if (threadIdx.x == 255) partials[blockIdx.x] = tmp[255];
}

__global__ __launch_bounds__(512) void k_scan2(int* __restrict__ partials, int nb) {
    __shared__ int tmp[512];
    int v = (threadIdx.x < nb) ? partials[threadIdx.x] : 0;
    tmp[threadIdx.x] = v;
    __syncthreads();
    for (int off = 1; off < 512; off <<= 1) {
        int t = (threadIdx.x >= off) ? tmp[threadIdx.x - off] : 0;
        __syncthreads();
        tmp[threadIdx.x] += t;
        __syncthreads();
    }
    if (threadIdx.x < nb) partials[threadIdx.x] = tmp[threadIdx.x] - v;  // exclusive
}

__global__ __launch_bounds__(256) void k_scan3(int* __restrict__ work,
                                               const int* __restrict__ partials, int n) {
    int i = blockIdx.x * 256 + threadIdx.x;
    if (i < n) work[i] += partials[blockIdx.x];
}

// ---------- seed bucket cursors from the node scan: bucketCur[b] = work[b*128] ----------

__global__ __launch_bounds__(1024) void k_bcur(const int* __restrict__ work,
                                               int* __restrict__ bucketCur, int n) {
    int b = threadIdx.x;
    int node = b << 7;
    bucketCur[b] = (node < n) ? work[node] : 0;
}

// ---------- pass B: bin edges into bucket-contiguous ebuf (8B packed) ----------

__global__ __launch_bounds__(256) void k_binfill(const int* __restrict__ src,
                                                 const int* __restrict__ dst,
                                                 int* __restrict__ bucketCur,
                                                 unsigned long long* __restrict__ ebuf,
                                                 int ne) {
    __shared__ int lcnt[NBKT];    // phase1: counts, phase3: local cursor
    __shared__ int lbase[NBKT];   // reserved global base per bucket
    const int e0 = blockIdx.x * 4096;
    for (int j = threadIdx.x; j < NBKT; j += 256) lcnt[j] = 0;
    __syncthreads();

    int dcache[16];
#pragma unroll
    for (int i = 0; i < 16; i++) {
        int e = e0 + i * 256 + threadIdx.x;
        int d = (e < ne) ? dst[e] : -1;
        dcache[i] = d;
        if (d >= 0) atomicAdd(&lcnt[d >> 7], 1);
    }
    __syncthreads();

    for (int j = threadIdx.x; j < NBKT; j += 256) {
        int c = lcnt[j];
        lbase[j] = c ? atomicAdd(&bucketCur[j], c) : 0;
        lcnt[j] = 0;      // safe: only this thread touches index j in this phase
    }
    __syncthreads();

#pragma unroll
    for (int i = 0; i < 16; i++) {
        int e = e0 + i * 256 + threadIdx.x;
        if (e < ne) {
            int d = dcache[i];
            int s = src[e];
            int b = d >> 7;
            int lp = atomicAdd(&lcnt[b], 1);
            ebuf[lbase[b] + lp] =
                ((unsigned long long)(unsigned)d << 32) | (unsigned)s;
        }
    }
}

// ---------- pass C: exact fill within bucket; LDS cursors, L2-hot csr window ----------

__global__ __launch_bounds__(256) void k_bucketfill(const unsigned long long* __restrict__ ebuf,
                                                    const int* __restrict__ work,
                                                    int* __restrict__ csr,
                                                    int n, int ne) {
    __shared__ int cur[128];
    const int b = blockIdx.x;
    const int base = b << 7;
    const int nodes = min(128, n - base);
    if (threadIdx.x < nodes) cur[threadIdx.x] = work[base + threadIdx.x];
    __syncthreads();
    const int beg = work[base];
    const int endn = base + 128;
    const int end = (endn < n) ? work[endn] : ne;
    for (int i = beg + threadIdx.x; i < end; i += 256) {
        unsigned long long p = ebuf[i];
        int d = (int)(p >> 32);
        int s = (int)(p & 0xffffffffu);
        int pos = atomicAdd(&cur[d & 127], 1);
        csr[pos] = s;
    }
}

// ---------- W transpose + fp16 cast: T[n][k] = (fp16) W[k][n] ----------

__global__ __launch_bounds__(256) void k_transW(const float* __restrict__ W1,
                                                const float* __restrict__ W2,
                                                _Float16* __restrict__ T1,
                                                _Float16* __restrict__ T2) {
    int b = blockIdx.x;                       // 0..127
    const float* W = (b < 64) ? W1 : W2;
    _Float16* T = (b < 64) ? T1 : T2;
    int idx = (b & 63) * 256 + threadIdx.x;   // 0..16383
    int k = idx >> 7, nn = idx & 127;
    T[nn * FDIM + k] = (_Float16)W[idx];
}

// ---------- MFMA GEMM: H(fp16) = dinv[r] * (X @ W)  (M x 128 x 128) ----------

template <typename T>
__global__ __launch_bounds__(256) void k_gemm_f16(const T* __restrict__ X,
                                                  const _Float16* __restrict__ WT,
                                                  const float* __restrict__ dinv,
                                                  _Float16* __restrict__ H, int n) {
    __shared__ _Float16 sA[FDIM * FDIM];   // 32 KB
    __shared__ _Float16 sB[FDIM * FDIM];   // 32 KB
    const int t = threadIdx.x;
    const int lane = t & 63;
    const int w = t >> 6;
    const int rowhalf = w >> 1, colhalf = w & 1;

    for (int i = 0; i < 8; i++) {          // stage W^T once
        int f = i * 256 + t;
        int nn = f >> 4, g = f & 15;
        ((float4*)sB)[nn * 16 + ((g ^ nn) & 15)] = ((const float4*)WT)[f];
    }

    const int ntiles = (n + 127) >> 7;
    for (int tile = blockIdx.x; tile < ntiles; tile += gridDim.x) {
        const int R0 = tile << 7;
        __syncthreads();                    // frag readers done / sB staged
        for (int i = 0; i < 8; i++) {
            int f = i * 256 + t;
            int row = f >> 4, g = f & 15;
            int gr = min(R0 + row, n - 1);
            h8 val;
            if constexpr (sizeof(T) == 4) {
                const float4* xp = (const float4*)(X + (size_t)gr * FDIM + g * 8);
                float4 u0 = xp[0], u1 = xp[1];
                val[0] = (_Float16)u0.x; val[1] = (_Float16)u0.y;
                val[2] = (_Float16)u0.z; val[3] = (_Float16)u0.w;
                val[4] = (_Float16)u1.x; val[5] = (_Float16)u1.y;
                val[6] = (_Float16)u1.z; val[7] = (_Float16)u1.w;
            } else {
                val = ((const h8*)(X + (size_t)gr * FDIM))[g];
            }
            ((h8*)sA)[row * 16 + ((g ^ row) & 15)] = val;
        }
        __syncthreads();

        v4f acc[4][4];
#pragma unroll
        for (int rt = 0; rt < 4; rt++)
#pragma unroll
            for (int ct = 0; ct < 4; ct++)
                acc[rt][ct] = (v4f){0.f, 0.f, 0.f, 0.f};

#pragma unroll
        for (int s = 0; s < 4; s++) {
            const int g0 = s * 4 + (lane >> 4);
            h8 af[4], bf[4];
#pragma unroll
            for (int rt = 0; rt < 4; rt++) {
                int row = rowhalf * 64 + rt * 16 + (lane & 15);
                af[rt] = ((const h8*)sA)[row * 16 + ((g0 ^ row) & 15)];
            }
#pragma unroll
            for (int ct = 0; ct < 4; ct++) {
                int nn = colhalf * 64 + ct * 16 + (lane & 15);
                bf[ct] = ((const h8*)sB)[nn * 16 + ((g0 ^ nn) & 15)];
            }
#pragma unroll
            for (int rt = 0; rt < 4; rt++)
#pragma unroll
                for (int ct = 0; ct < 4; ct++)
                    acc[rt][ct] = __builtin_amdgcn_mfma_f32_16x16x32_f16(
                        af[rt], bf[ct], acc[rt][ct], 0, 0, 0);
        }

        // epilogue: C/D layout col = lane&15, row = (lane>>4)*4 + reg; fuse dinv
        const int rb = R0 + rowhalf * 64 + (lane >> 4) * 4;
        const int cb = colhalf * 64 + (lane & 15);
#pragma unroll
        for (int rt = 0; rt < 4; rt++)
#pragma unroll
            for (int reg = 0; reg < 4; reg++) {
                int grow = rb + rt * 16 + reg;
                if (grow < n) {
                    float d = dinv[grow];
                    _Float16* hp = H + (size_t)grow * FDIM + cb;
#pragma unroll
                    for (int ct = 0; ct < 4; ct++)
                        hp[ct * 16] = (_Float16)(acc[rt][ct][reg] * d);
                }
            }
    }
}

// ---------- gather aggregate (fp16 pre-scaled messages, fp32 accumulate) ----------
// hs[r] = dinv[r]*(XW)[r];  out[d] = relu(dinv[d]*(hs[d] + sum_s hs[s]) + b).
// 4-wide unrolled gather: 4 independent loads in flight per wave.

__global__ __launch_bounds__(256) void k_aggregate(const int* __restrict__ work,
                                                   const int* __restrict__ csr,
                                                   const float* __restrict__ dinv,
                                                   const _Float16* __restrict__ hs,
                                                   const float* __restrict__ bias,
                                                   _Float16* __restrict__ out,
                                                   int n, int ne) {
    const int lane = threadIdx.x & 63;
    const int nwaves = gridDim.x * 4;
    int wid = (blockIdx.x * 256 + threadIdx.x) >> 6;
    const h2* hs2 = (const h2*)hs;
    const float2 bb = ((const float2*)bias)[lane];

    for (int node = wid; node < n; node += nwaves) {
        int beg = work[node];
        int end = (node + 1 < n) ? work[node + 1] : ne;
        float dd = dinv[node];
        h2 hv = hs2[(size_t)node * 64 + lane];
        float ax = (float)hv[0];
        float ay = (float)hv[1];
        for (int chunk = beg; chunk < end; chunk += 64) {
            int m = end - chunk; if (m > 64) m = 64;
            int myidx = (lane < m) ? csr[chunk + lane] : 0;
            int j = 0;
            for (; j + 4 <= m; j += 4) {
                int s0 = __shfl(myidx, j + 0);
                int s1 = __shfl(myidx, j + 1);
                int s2 = __shfl(myidx, j + 2);
                int s3 = __shfl(myidx, j + 3);
                h2 v0 = hs2[(size_t)s0 * 64 + lane];
                h2 v1 = hs2[(size_t)s1 * 64 + lane];
                h2 v2 = hs2[(size_t)s2 * 64 + lane];
                h2 v3 = hs2[(size_t)s3 * 64 + lane];
                ax += (float)v0[0] + (float)v1[0] + (float)v2[0] + (float)v3[0];
                ay += (float)v0[1] + (float)v1[1] + (float)v2[1] + (float)v3[1];
            }
            for (; j < m; j++) {
                int s = __shfl(myidx, j);
                h2 v = hs2[(size_t)s * 64 + lane];
                ax += (float)v[0];
                ay += (float)v[1];
            }
        }
        float ox = fmaxf(ax * dd + bb.x, 0.f);
        float oy = fmaxf(ay * dd + bb.y, 0.f);
        h2 o; o[0] = (_Float16)ox; o[1] = (_Float16)oy;
        ((h2*)out)[(size_t)node * 64 + lane] = o;
    }
}

// ---------- pools ----------

__global__ __launch_bounds__(256) void k_pool_h(const _Float16* __restrict__ X,
                                                float* __restrict__ colsum,
                                                float* __restrict__ colmax, int n) {
    __shared__ float ls[256], lm[256];
    int c = threadIdx.x & 127;
    int grp = threadIdx.x >> 7;
    float s = 0.f, m = 0.f;
    for (int r = blockIdx.x * 2 + grp; r < n; r += gridDim.x * 2) {
        float v = (float)X[(size_t)r * FDIM + c];
        s += v;
        m = fmaxf(m, v);
    }
    ls[threadIdx.x] = s;
    lm[threadIdx.x] = m;
    __syncthreads();
    if (threadIdx.x < 128) {
        s = ls[threadIdx.x] + ls[threadIdx.x + 128];
        m = fmaxf(lm[threadIdx.x], lm[threadIdx.x + 128]);
        unsafeAtomicAdd(&colsum[c], s);
        atomicMax((int*)colmax + c, __float_as_int(m));
    }
}

__global__ __launch_bounds__(256) void k_pool_f(const float* __restrict__ X,
                                                float* __restrict__ colsum,
                                                float* __restrict__ colmax, int n) {
    __shared__ float ls[256], lm[256];
    int c = threadIdx.x & 127;
    int grp = threadIdx.x >> 7;
    float s = 0.f, m = 0.f;
    for (int r = blockIdx.x * 2 + grp; r < n; r += gridDim.x * 2) {
        float v = X[(size_t)r * FDIM + c];
        s += v;
        m = fmaxf(m, v);
    }
    ls[threadIdx.x] = s;
    lm[threadIdx.x] = m;
    __syncthreads();
    if (threadIdx.x < 128) {
        s = ls[threadIdx.x] + ls[threadIdx.x + 128];
        m = fmaxf(lm[threadIdx.x], lm[threadIdx.x + 128]);
        unsafeAtomicAdd(&colsum[c], s);
        atomicMax((int*)colmax + c, __float_as_int(m));
    }
}

__global__ __launch_bounds__(256) void k_fc(const float* __restrict__ colsum,
                                            const float* __restrict__ colmax,
                                            const float* __restrict__ fcW,
                                            const float* __restrict__ fcb,
                                            float* __restrict__ out, float invN) {
    int o = threadIdx.x;
    float acc = fcb[o];
#pragma unroll 4
    for (int k = 0; k < FDIM; k++)
        acc += colsum[k] * invN * fcW[k * 256 + o];
#pragma unroll 4
    for (int k = 0; k < FDIM; k++)
        acc += colmax[k] * fcW[(FDIM + k) * 256 + o];
    out[o] = acc;
}

// ================= fallback (round-1 atomic scatter, fp32) =================

__global__ __launch_bounds__(256) void k_initF(float* deg, float* cs, float* cm, int n) {
    int i = blockIdx.x * 256 + threadIdx.x;
    if (i < n) deg[i] = 1.0f;
    if (i < FDIM) { cs[i] = 0.0f; cm[i] = 0.0f; }
}
__global__ __launch_bounds__(256) void k_degreeF(const int* dst, float* deg, int ne) {
    int i = blockIdx.x * 256 + threadIdx.x;
    if (i < ne) unsafeAtomicAdd(&deg[dst[i]], 1.0f);
}
__global__ __launch_bounds__(256) void k_rsqrtF(float* deg, int n) {
    int i = blockIdx.x * 256 + threadIdx.x;
    if (i < n) deg[i] = 1.0f / sqrtf(deg[i]);
}
__global__ __launch_bounds__(256) void k_selfinitF(const float* H, const float* dinv,
                                                   float* acc, int n) {
    int i = blockIdx.x * 256 + threadIdx.x;
    if (i >= n * 32) return;
    int row = i >> 5;
    float s = dinv[row]; s *= s;
    float4 v = ((const float4*)H)[i];
    v.x *= s; v.y *= s; v.z *= s; v.w *= s;
    ((float4*)acc)[i] = v;
}
__global__ __launch_bounds__(256) void k_scatterF(const int* src, const int* dst,
                                                  const float* dinv, const float* H,
                                                  float* acc, int ne) {
    int e = (blockIdx.x * 256 + threadIdx.x) >> 6;
    if (e >= ne) return;
    int lane = threadIdx.x & 63;
    int s = src[e], d = dst[e];
    float w = dinv[s] * dinv[d];
    float2 v = ((const float2*)(H + (size_t)s * FDIM))[lane];
    float* ap = acc + (size_t)d * FDIM + lane * 2;
    unsafeAtomicAdd(ap, v.x * w);
    unsafeAtomicAdd(ap + 1, v.y * w);
}
__global__ __launch_bounds__(256) void k_bias_reluF(float* acc, const float* b, int n) {
    int i = blockIdx.x * 256 + threadIdx.x;
    if (i >= n * 32) return;
    float4 bb = ((const float4*)b)[i & 31];
    float4 v = ((float4*)acc)[i];
    v.x = fmaxf(v.x + bb.x, 0.f);
    v.y = fmaxf(v.y + bb.y, 0.f);
    v.z = fmaxf(v.z + bb.z, 0.f);
    v.w = fmaxf(v.w + bb.w, 0.f);
    ((float4*)acc)[i] = v;
}
__global__ __launch_bounds__(256) void k_gemm128F(const float* X, const float* W,
                                                   float* H, int n) {
    __shared__ float sW[FDIM * FDIM];
    for (int i = threadIdx.x; i < FDIM * FDIM / 4; i += 256)
        ((float4*)sW)[i] = ((const float4*)W)[i];
    __syncthreads();
    const int c = threadIdx.x & 127;
    const int half = threadIdx.x >> 7;
    for (int base = blockIdx.x * 8; base < n; base += gridDim.x * 8) {
        const int r0 = base + half * 4;
        const float* xp0 = X + (size_t)min(r0 + 0, n - 1) * FDIM;
        const float* xp1 = X + (size_t)min(r0 + 1, n - 1) * FDIM;
        const float* xp2 = X + (size_t)min(r0 + 2, n - 1) * FDIM;
        const float* xp3 = X + (size_t)min(r0 + 3, n - 1) * FDIM;
        float a0 = 0.f, a1 = 0.f, a2 = 0.f, a3 = 0.f;
#pragma unroll 8
        for (int k = 0; k < FDIM; k += 4) {
            float w0 = sW[(k + 0) * FDIM + c];
            float w1 = sW[(k + 1) * FDIM + c];
            float w2 = sW[(k + 2) * FDIM + c];
            float w3 = sW[(k + 3) * FDIM + c];
            float4 x0 = *(const float4*)(xp0 + k);
            float4 x1 = *(const float4*)(xp1 + k);
            float4 x2 = *(const float4*)(xp2 + k);
            float4 x3 = *(const float4*)(xp3 + k);
            a0 += x0.x * w0 + x0.y * w1 + x0.z * w2 + x0.w * w3;
            a1 += x1.x * w0 + x1.y * w1 + x1.z * w2 + x1.w * w3;
            a2 += x2.x * w0 + x2.y * w1 + x2.z * w2 + x2.w * w3;
            a3 += x3.x * w0 + x3.y * w1 + x3.z * w2 + x3.w * w3;
        }
        if (r0 + 0 < n) H[(size_t)(r0 + 0) * FDIM + c] = a0;
        if (r0 + 1 < n) H[(size_t)(r0 + 1) * FDIM + c] = a1;
        if (r0 + 2 < n) H[(size_t)(r0 + 2) * FDIM + c] = a2;
        if (r0 + 3 < n) H[(size_t)(r0 + 3) * FDIM + c] = a3;
    }
}

// ================= launch =================

extern "C" void kernel_launch(void* const* d_in, const int* in_sizes, int n_in,
                              void* d_out, int out_size, void* d_ws, size_t ws_size,
                              hipStream_t stream) {
    const float* X   = (const float*)d_in[0];
    const int*   ei  = (const int*)d_in[1];
    const float* W1  = (const float*)d_in[2];
    const float* b1  = (const float*)d_in[3];
    const float* W2  = (const float*)d_in[4];
    const float* b2  = (const float*)d_in[5];
    const float* fcW = (const float*)d_in[6];
    const float* fcb = (const float*)d_in[7];
    float* out = (float*)d_out;

    const int n  = in_sizes[0] / FDIM;    // 100000
    const int ne = in_sizes[1] / 2;       // 1600000
    const int* src = ei;
    const int* dst = ei + ne;

    const int gN = (n + 255) / 256;
    const int gE = (ne + 255) / 256;
    const int nbkt = (n + 127) >> 7;      // real bucket count (<= NBKT)
    const int gB = (ne + 4095) / 4096;    // binfill blocks

    size_t need = (size_t)ne * 8 + (size_t)n * FDIM * 2 * 2 + 2 * FDIM * FDIM * 2 +
                  ((size_t)n + 2 * FDIM) * 4 +
                  ((size_t)n * 2 + 512 + NBKT + ne) * 4;

    if (ws_size >= need && gN <= 512 && nbkt <= NBKT) {
        unsigned long long* ebuf = (unsigned long long*)d_ws;
        _Float16* h    = (_Float16*)(ebuf + ne);
        _Float16* xbuf = h + (size_t)n * FDIM;
        _Float16* w1t  = xbuf + (size_t)n * FDIM;
        _Float16* w2t  = w1t + FDIM * FDIM;
        float* dinv    = (float*)(w2t + FDIM * FDIM);
        float* colsum  = dinv + n;
        float* colmax  = colsum + FDIM;
        int* counts    = (int*)(colmax + FDIM);
        int* work      = counts + n;
        int* partials  = work + n;
        int* bucketCur = partials + 512;
        int* csr       = bucketCur + NBKT;

        k_zero_init<<<gN, 256, 0, stream>>>(counts, colsum, colmax, n);
        k_hist<<<gE, 256, 0, stream>>>(dst, counts, ne);
        k_dinv<<<gN, 256, 0, stream>>>(counts, dinv, n);
        k_scan1<<<gN, 256, 0, stream>>>(counts, work, partials, n);
        k_scan2<<<1, 512, 0, stream>>>(partials, gN);
        k_scan3<<<gN, 256, 0, stream>>>(work, partials, n);
        k_bcur<<<1, NBKT, 0, stream>>>(work, bucketCur, n);
        k_binfill<<<gB, 256, 0, stream>>>(src, dst, bucketCur, ebuf, ne);
        k_bucketfill<<<nbkt, 256, 0, stream>>>(ebuf, work, csr, n, ne);
        k_transW<<<128, 256, 0, stream>>>(W1, W2, w1t, w2t);

        k_gemm_f16<float><<<512, 256, 0, stream>>>(X, w1t, dinv, h, n);
        k_aggregate<<<2048, 256, 0, stream>>>(work, csr, dinv, h, b1, xbuf, n, ne);
        k_gemm_f16<_Float16><<<512, 256, 0, stream>>>(xbuf, w2t, dinv, h, n);
        k_aggregate<<<2048, 256, 0, stream>>>(work, csr, dinv, h, b2, xbuf, n, ne);

        k_pool_h<<<1024, 256, 0, stream>>>(xbuf, colsum, colmax, n);
        k_fc<<<1, 256, 0, stream>>>(colsum, colmax, fcW, fcb, out, 1.0f / (float)n);
    } else {
        float* h      = (float*)d_ws;
        float* acc    = h + (size_t)n * FDIM;
        float* dinv   = acc + (size_t)n * FDIM;
        float* colsum = dinv + n;
        float* colmax = colsum + FDIM;
        const int gV = (n * 32 + 255) / 256;
        const int gS = (int)(((long long)ne * 64 + 255) / 256);

        k_initF<<<gN, 256, 0, stream>>>(dinv, colsum, colmax, n);
        k_degreeF<<<gE, 256, 0, stream>>>(dst, dinv, ne);
        k_rsqrtF<<<gN, 256, 0, stream>>>(dinv, n);

        k_gemm128F<<<1024, 256, 0, stream>>>(X, W1, h, n);
        k_selfinitF<<<gV, 256, 0, stream>>>(h, dinv, acc, n);
        k_scatterF<<<gS, 256, 0, stream>>>(src, dst, dinv, h, acc, ne);
        k_bias_reluF<<<gV, 256, 0, stream>>>(acc, b1, n);

        k_gemm128F<<<1024, 256, 0, stream>>>(acc, W2, h, n);
        k_selfinitF<<<gV, 256, 0, stream>>>(h, dinv, acc, n);
        k_scatterF<<<gS, 256, 0, stream>>>(src, dst, dinv, h, acc, ne);
        k_bias_reluF<<<gV, 256, 0, stream>>>(acc, b2, n);

        k_pool_f<<<1024, 256, 0, stream>>>(acc, colsum, colmax, n);
        k_fc<<<1, 256, 0, stream>>>(colsum, colmax, fcW, fcb, out, 1.0f / (float)n);
    }
}

// Round 8
// 387.807 us; speedup vs baseline: 2.2695x; 1.1282x over previous
//
#include <hip/hip_runtime.h>
#include <hip/hip_bf16.h>
#include <hip/hip_fp16.h>

static constexpr int FDIM = 128;
static constexpr int NBKT = 1024;       // padded bucket count (bucket = dst>>7)
static constexpr int BHB = 128;         // k_bhist blocks (partial histograms)

typedef _Float16 h8 __attribute__((ext_vector_type(8)));
typedef _Float16 h2 __attribute__((ext_vector_type(2)));
typedef float v4f __attribute__((ext_vector_type(4)));

// ================= CSR build (all node-level atomics in LDS) =================

__global__ __launch_bounds__(256) void k_zero128(float* __restrict__ colsum,
                                                 float* __restrict__ colmax) {
    int i = threadIdx.x;
    if (i < FDIM) { colsum[i] = 0.0f; colmax[i] = 0.0f; }
}

// per-block bucket histogram -> private partials (no global atomics)
__global__ __launch_bounds__(256) void k_bhist(const int* __restrict__ dst,
                                               int* __restrict__ bucketPart, int ne) {
    __shared__ int lb[NBKT];
    for (int j = threadIdx.x; j < NBKT; j += 256) lb[j] = 0;
    __syncthreads();
    int stride = gridDim.x * 256;
    for (int e = blockIdx.x * 256 + threadIdx.x; e < ne; e += stride)
        atomicAdd(&lb[dst[e] >> 7], 1);
    __syncthreads();
    int* mine = bucketPart + blockIdx.x * NBKT;
    for (int j = threadIdx.x; j < NBKT; j += 256) mine[j] = lb[j];
}

// reduce partials + exclusive scan -> bucketBase, bucketCur
__global__ __launch_bounds__(1024) void k_scanB(const int* __restrict__ bucketPart,
                                                int* __restrict__ bucketBase,
                                                int* __restrict__ bucketCur) {
    __shared__ int tmp[NBKT];
    int t = threadIdx.x;
    int v = 0;
    for (int k = 0; k < BHB; k++) v += bucketPart[k * NBKT + t];
    tmp[t] = v;
    __syncthreads();
    for (int off = 1; off < NBKT; off <<= 1) {
        int u = (t >= off) ? tmp[t - off] : 0;
        __syncthreads();
        tmp[t] += u;
        __syncthreads();
    }
    int excl = tmp[t] - v;
    bucketBase[t] = excl;
    bucketCur[t] = excl;
}

// bin edges into bucket-contiguous ebuf (8B packed), 8192 edges/block:
// LDS histogram -> one global reservation atomic per touched bucket -> scatter
__global__ __launch_bounds__(256) void k_binfill(const int* __restrict__ src,
                                                 const int* __restrict__ dst,
                                                 int* __restrict__ bucketCur,
                                                 unsigned long long* __restrict__ ebuf,
                                                 int ne) {
    __shared__ int lcnt[NBKT];    // phase1: counts, phase3: local cursor
    __shared__ int lbase[NBKT];   // reserved global base per bucket
    const int e0 = blockIdx.x * 8192;
    for (int j = threadIdx.x; j < NBKT; j += 256) lcnt[j] = 0;
    __syncthreads();

    int dcache[32];
#pragma unroll
    for (int i = 0; i < 32; i++) {
        int e = e0 + i * 256 + threadIdx.x;
        int d = (e < ne) ? dst[e] : -1;
        dcache[i] = d;
        if (d >= 0) atomicAdd(&lcnt[d >> 7], 1);
    }
    __syncthreads();

    for (int j = threadIdx.x; j < NBKT; j += 256) {
        int c = lcnt[j];
        lbase[j] = c ? atomicAdd(&bucketCur[j], c) : 0;
        lcnt[j] = 0;      // safe: only this thread touches index j in this phase
    }
    __syncthreads();

#pragma unroll
    for (int i = 0; i < 32; i++) {
        int e = e0 + i * 256 + threadIdx.x;
        if (e < ne) {
            int d = dcache[i];
            int s = src[e];
            int b = d >> 7;
            int lp = atomicAdd(&lcnt[b], 1);
            ebuf[lbase[b] + lp] =
                ((unsigned long long)(unsigned)d << 32) | (unsigned)s;
        }
    }
}

// per bucket: count 128 nodes (LDS), scan (LDS), emit work/dinv, fill csr.
// bucket b's ebuf range is [bucketBase[b], bucketEnd[b]).
__global__ __launch_bounds__(256) void k_bucketproc(const unsigned long long* __restrict__ ebuf,
                                                    const int* __restrict__ bucketBase,
                                                    const int* __restrict__ bucketEnd,
                                                    int* __restrict__ work,
                                                    float* __restrict__ dinv,
                                                    int* __restrict__ csr, int n) {
    __shared__ int cnt[128];
    __shared__ int scn[128];
    const int b = blockIdx.x;
    const int base = b << 7;
    const int beg = bucketBase[b], end = bucketEnd[b];

    if (threadIdx.x < 128) cnt[threadIdx.x] = 0;
    __syncthreads();
    for (int i = beg + threadIdx.x; i < end; i += 256) {
        int d = (int)(ebuf[i] >> 32);
        atomicAdd(&cnt[d & 127], 1);
    }
    __syncthreads();

    int v = 0;
    if (threadIdx.x < 128) { v = cnt[threadIdx.x]; scn[threadIdx.x] = v; }
    __syncthreads();
    for (int off = 1; off < 128; off <<= 1) {
        int t = 0;
        if (threadIdx.x < 128 && threadIdx.x >= off) t = scn[threadIdx.x - off];
        __syncthreads();
        if (threadIdx.x < 128) scn[threadIdx.x] += t;
        __syncthreads();
    }
    if (threadIdx.x < 128) {
        int node = base + threadIdx.x;
        if (node < n) {
            int w = beg + scn[threadIdx.x] - v;      // exclusive within bucket
            work[node] = w;
            dinv[node] = 1.0f / sqrtf(1.0f + (float)v);
            cnt[threadIdx.x] = w;                    // reuse as cursor
        }
    }
    __syncthreads();

    for (int i = beg + threadIdx.x; i < end; i += 256) {
        unsigned long long p = ebuf[i];
        int d = (int)(p >> 32);
        int s = (int)(p & 0xffffffffu);
        int pos = atomicAdd(&cnt[d & 127], 1);
        csr[pos] = s;
    }
}

// ---------- W transpose + fp16 cast: T[n][k] = (fp16) W[k][n] ----------

__global__ __launch_bounds__(256) void k_transW(const float* __restrict__ W1,
                                                const float* __restrict__ W2,
                                                _Float16* __restrict__ T1,
                                                _Float16* __restrict__ T2) {
    int b = blockIdx.x;                       // 0..127
    const float* W = (b < 64) ? W1 : W2;
    _Float16* T = (b < 64) ? T1 : T2;
    int idx = (b & 63) * 256 + threadIdx.x;   // 0..16383
    int k = idx >> 7, nn = idx & 127;
    T[nn * FDIM + k] = (_Float16)W[idx];
}

// ---------- MFMA GEMM: H(fp16) = dinv[r] * (X @ W)  (M x 128 x 128) ----------

template <typename T>
__global__ __launch_bounds__(256) void k_gemm_f16(const T* __restrict__ X,
                                                  const _Float16* __restrict__ WT,
                                                  const float* __restrict__ dinv,
                                                  _Float16* __restrict__ H, int n) {
    __shared__ _Float16 sA[FDIM * FDIM];   // 32 KB
    __shared__ _Float16 sB[FDIM * FDIM];   // 32 KB
    const int t = threadIdx.x;
    const int lane = t & 63;
    const int w = t >> 6;
    const int rowhalf = w >> 1, colhalf = w & 1;

    for (int i = 0; i < 8; i++) {          // stage W^T once
        int f = i * 256 + t;
        int nn = f >> 4, g = f & 15;
        ((float4*)sB)[nn * 16 + ((g ^ nn) & 15)] = ((const float4*)WT)[f];
    }

    const int ntiles = (n + 127) >> 7;
    for (int tile = blockIdx.x; tile < ntiles; tile += gridDim.x) {
        const int R0 = tile << 7;
        __syncthreads();                    // frag readers done / sB staged
        for (int i = 0; i < 8; i++) {
            int f = i * 256 + t;
            int row = f >> 4, g = f & 15;
            int gr = min(R0 + row, n - 1);
            h8 val;
            if constexpr (sizeof(T) == 4) {
                const float4* xp = (const float4*)(X + (size_t)gr * FDIM + g * 8);
                float4 u0 = xp[0], u1 = xp[1];
                val[0] = (_Float16)u0.x; val[1] = (_Float16)u0.y;
                val[2] = (_Float16)u0.z; val[3] = (_Float16)u0.w;
                val[4] = (_Float16)u1.x; val[5] = (_Float16)u1.y;
                val[6] = (_Float16)u1.z; val[7] = (_Float16)u1.w;
            } else {
                val = ((const h8*)(X + (size_t)gr * FDIM))[g];
            }
            ((h8*)sA)[row * 16 + ((g ^ row) & 15)] = val;
        }
        __syncthreads();

        v4f acc[4][4];
#pragma unroll
        for (int rt = 0; rt < 4; rt++)
#pragma unroll
            for (int ct = 0; ct < 4; ct++)
                acc[rt][ct] = (v4f){0.f, 0.f, 0.f, 0.f};

#pragma unroll
        for (int s = 0; s < 4; s++) {
            const int g0 = s * 4 + (lane >> 4);
            h8 af[4], bf[4];
#pragma unroll
            for (int rt = 0; rt < 4; rt++) {
                int row = rowhalf * 64 + rt * 16 + (lane & 15);
                af[rt] = ((const h8*)sA)[row * 16 + ((g0 ^ row) & 15)];
            }
#pragma unroll
            for (int ct = 0; ct < 4; ct++) {
                int nn = colhalf * 64 + ct * 16 + (lane & 15);
                bf[ct] = ((const h8*)sB)[nn * 16 + ((g0 ^ nn) & 15)];
            }
#pragma unroll
            for (int rt = 0; rt < 4; rt++)
#pragma unroll
                for (int ct = 0; ct < 4; ct++)
                    acc[rt][ct] = __builtin_amdgcn_mfma_f32_16x16x32_f16(
                        af[rt], bf[ct], acc[rt][ct], 0, 0, 0);
        }

        // epilogue: C/D layout col = lane&15, row = (lane>>4)*4 + reg; fuse dinv
        const int rb = R0 + rowhalf * 64 + (lane >> 4) * 4;
        const int cb = colhalf * 64 + (lane & 15);
#pragma unroll
        for (int rt = 0; rt < 4; rt++)
#pragma unroll
            for (int reg = 0; reg < 4; reg++) {
                int grow = rb + rt * 16 + reg;
                if (grow < n) {
                    float d = dinv[grow];
                    _Float16* hp = H + (size_t)grow * FDIM + cb;
#pragma unroll
                    for (int ct = 0; ct < 4; ct++)
                        hp[ct * 16] = (_Float16)(acc[rt][ct][reg] * d);
                }
            }
    }
}

// ---------- gather aggregate (fp16 pre-scaled messages, fp32 accumulate) ----------
// hs[r] = dinv[r]*(XW)[r];  out[d] = relu(dinv[d]*(hs[d] + sum_s hs[s]) + b).

__global__ __launch_bounds__(256) void k_aggregate(const int* __restrict__ work,
                                                   const int* __restrict__ csr,
                                                   const float* __restrict__ dinv,
                                                   const _Float16* __restrict__ hs,
                                                   const float* __restrict__ bias,
                                                   _Float16* __restrict__ out,
                                                   int n, int ne) {
    const int lane = threadIdx.x & 63;
    const int nwaves = gridDim.x * 4;
    int wid = (blockIdx.x * 256 + threadIdx.x) >> 6;
    const h2* hs2 = (const h2*)hs;
    const float2 bb = ((const float2*)bias)[lane];

    for (int node = wid; node < n; node += nwaves) {
        int beg = work[node];
        int end = (node + 1 < n) ? work[node + 1] : ne;
        float dd = dinv[node];
        h2 hv = hs2[(size_t)node * 64 + lane];
        float ax = (float)hv[0];
        float ay = (float)hv[1];
        for (int chunk = beg; chunk < end; chunk += 64) {
            int m = end - chunk; if (m > 64) m = 64;
            int myidx = (lane < m) ? csr[chunk + lane] : 0;
            int j = 0;
            for (; j + 4 <= m; j += 4) {
                int s0 = __shfl(myidx, j + 0);
                int s1 = __shfl(myidx, j + 1);
                int s2 = __shfl(myidx, j + 2);
                int s3 = __shfl(myidx, j + 3);
                h2 v0 = hs2[(size_t)s0 * 64 + lane];
                h2 v1 = hs2[(size_t)s1 * 64 + lane];
                h2 v2 = hs2[(size_t)s2 * 64 + lane];
                h2 v3 = hs2[(size_t)s3 * 64 + lane];
                ax += (float)v0[0] + (float)v1[0] + (float)v2[0] + (float)v3[0];
                ay += (float)v0[1] + (float)v1[1] + (float)v2[1] + (float)v3[1];
            }
            for (; j < m; j++) {
                int s = __shfl(myidx, j);
                h2 v = hs2[(size_t)s * 64 + lane];
                ax += (float)v[0];
                ay += (float)v[1];
            }
        }
        float ox = fmaxf(ax * dd + bb.x, 0.f);
        float oy = fmaxf(ay * dd + bb.y, 0.f);
        h2 o; o[0] = (_Float16)ox; o[1] = (_Float16)oy;
        ((h2*)out)[(size_t)node * 64 + lane] = o;
    }
}

// ---------- pools ----------

__global__ __launch_bounds__(256) void k_pool_h(const _Float16* __restrict__ X,
                                                float* __restrict__ colsum,
                                                float* __restrict__ colmax, int n) {
    __shared__ float ls[256], lm[256];
    int c = threadIdx.x & 127;
    int grp = threadIdx.x >> 7;
    float s = 0.f, m = 0.f;
    for (int r = blockIdx.x * 2 + grp; r < n; r += gridDim.x * 2) {
        float v = (float)X[(size_t)r * FDIM + c];
        s += v;
        m = fmaxf(m, v);
    }
    ls[threadIdx.x] = s;
    lm[threadIdx.x] = m;
    __syncthreads();
    if (threadIdx.x < 128) {
        s = ls[threadIdx.x] + ls[threadIdx.x + 128];
        m = fmaxf(lm[threadIdx.x], lm[threadIdx.x + 128]);
        unsafeAtomicAdd(&colsum[c], s);
        atomicMax((int*)colmax + c, __float_as_int(m));
    }
}

__global__ __launch_bounds__(256) void k_pool_f(const float* __restrict__ X,
                                                float* __restrict__ colsum,
                                                float* __restrict__ colmax, int n) {
    __shared__ float ls[256], lm[256];
    int c = threadIdx.x & 127;
    int grp = threadIdx.x >> 7;
    float s = 0.f, m = 0.f;
    for (int r = blockIdx.x * 2 + grp; r < n; r += gridDim.x * 2) {
        float v = X[(size_t)r * FDIM + c];
        s += v;
        m = fmaxf(m, v);
    }
    ls[threadIdx.x] = s;
    lm[threadIdx.x] = m;
    __syncthreads();
    if (threadIdx.x < 128) {
        s = ls[threadIdx.x] + ls[threadIdx.x + 128];
        m = fmaxf(lm[threadIdx.x], lm[threadIdx.x + 128]);
        unsafeAtomicAdd(&colsum[c], s);
        atomicMax((int*)colmax + c, __float_as_int(m));
    }
}

__global__ __launch_bounds__(256) void k_fc(const float* __restrict__ colsum,
                                            const float* __restrict__ colmax,
                                            const float* __restrict__ fcW,
                                            const float* __restrict__ fcb,
                                            float* __restrict__ out, float invN) {
    int o = threadIdx.x;
    float acc = fcb[o];
#pragma unroll 4
    for (int k = 0; k < FDIM; k++)
        acc += colsum[k] * invN * fcW[k * 256 + o];
#pragma unroll 4
    for (int k = 0; k < FDIM; k++)
        acc += colmax[k] * fcW[(FDIM + k) * 256 + o];
    out[o] = acc;
}

// ================= fallback (round-1 atomic scatter, fp32) =================

__global__ __launch_bounds__(256) void k_initF(float* deg, float* cs, float* cm, int n) {
    int i = blockIdx.x * 256 + threadIdx.x;
    if (i < n) deg[i] = 1.0f;
    if (i < FDIM) { cs[i] = 0.0f; cm[i] = 0.0f; }
}
__global__ __launch_bounds__(256) void k_degreeF(const int* dst, float* deg, int ne) {
    int i = blockIdx.x * 256 + threadIdx.x;
    if (i < ne) unsafeAtomicAdd(&deg[dst[i]], 1.0f);
}
__global__ __launch_bounds__(256) void k_rsqrtF(float* deg, int n) {
    int i = blockIdx.x * 256 + threadIdx.x;
    if (i < n) deg[i] = 1.0f / sqrtf(deg[i]);
}
__global__ __launch_bounds__(256) void k_selfinitF(const float* H, const float* dinv,
                                                   float* acc, int n) {
    int i = blockIdx.x * 256 + threadIdx.x;
    if (i >= n * 32) return;
    int row = i >> 5;
    float s = dinv[row]; s *= s;
    float4 v = ((const float4*)H)[i];
    v.x *= s; v.y *= s; v.z *= s; v.w *= s;
    ((float4*)acc)[i] = v;
}
__global__ __launch_bounds__(256) void k_scatterF(const int* src, const int* dst,
                                                  const float* dinv, const float* H,
                                                  float* acc, int ne) {
    int e = (blockIdx.x * 256 + threadIdx.x) >> 6;
    if (e >= ne) return;
    int lane = threadIdx.x & 63;
    int s = src[e], d = dst[e];
    float w = dinv[s] * dinv[d];
    float2 v = ((const float2*)(H + (size_t)s * FDIM))[lane];
    float* ap = acc + (size_t)d * FDIM + lane * 2;
    unsafeAtomicAdd(ap, v.x * w);
    unsafeAtomicAdd(ap + 1, v.y * w);
}
__global__ __launch_bounds__(256) void k_bias_reluF(float* acc, const float* b, int n) {
    int i = blockIdx.x * 256 + threadIdx.x;
    if (i >= n * 32) return;
    float4 bb = ((const float4*)b)[i & 31];
    float4 v = ((float4*)acc)[i];
    v.x = fmaxf(v.x + bb.x, 0.f);
    v.y = fmaxf(v.y + bb.y, 0.f);
    v.z = fmaxf(v.z + bb.z, 0.f);
    v.w = fmaxf(v.w + bb.w, 0.f);
    ((float4*)acc)[i] = v;
}
__global__ __launch_bounds__(256) void k_gemm128F(const float* X, const float* W,
                                                   float* H, int n) {
    __shared__ float sW[FDIM * FDIM];
    for (int i = threadIdx.x; i < FDIM * FDIM / 4; i += 256)
        ((float4*)sW)[i] = ((const float4*)W)[i];
    __syncthreads();
    const int c = threadIdx.x & 127;
    const int half = threadIdx.x >> 7;
    for (int base = blockIdx.x * 8; base < n; base += gridDim.x * 8) {
        const int r0 = base + half * 4;
        const float* xp0 = X + (size_t)min(r0 + 0, n - 1) * FDIM;
        const float* xp1 = X + (size_t)min(r0 + 1, n - 1) * FDIM;
        const float* xp2 = X + (size_t)min(r0 + 2, n - 1) * FDIM;
        const float* xp3 = X + (size_t)min(r0 + 3, n - 1) * FDIM;
        float a0 = 0.f, a1 = 0.f, a2 = 0.f, a3 = 0.f;
#pragma unroll 8
        for (int k = 0; k < FDIM; k += 4) {
            float w0 = sW[(k + 0) * FDIM + c];
            float w1 = sW[(k + 1) * FDIM + c];
            float w2 = sW[(k + 2) * FDIM + c];
            float w3 = sW[(k + 3) * FDIM + c];
            float4 x0 = *(const float4*)(xp0 + k);
            float4 x1 = *(const float4*)(xp1 + k);
            float4 x2 = *(const float4*)(xp2 + k);
            float4 x3 = *(const float4*)(xp3 + k);
            a0 += x0.x * w0 + x0.y * w1 + x0.z * w2 + x0.w * w3;
            a1 += x1.x * w0 + x1.y * w1 + x1.z * w2 + x1.w * w3;
            a2 += x2.x * w0 + x2.y * w1 + x2.z * w2 + x2.w * w3;
            a3 += x3.x * w0 + x3.y * w1 + x3.z * w2 + x3.w * w3;
        }
        if (r0 + 0 < n) H[(size_t)(r0 + 0) * FDIM + c] = a0;
        if (r0 + 1 < n) H[(size_t)(r0 + 1) * FDIM + c] = a1;
        if (r0 + 2 < n) H[(size_t)(r0 + 2) * FDIM + c] = a2;
        if (r0 + 3 < n) H[(size_t)(r0 + 3) * FDIM + c] = a3;
    }
}

// ================= launch =================

extern "C" void kernel_launch(void* const* d_in, const int* in_sizes, int n_in,
                              void* d_out, int out_size, void* d_ws, size_t ws_size,
                              hipStream_t stream) {
    const float* X   = (const float*)d_in[0];
    const int*   ei  = (const int*)d_in[1];
    const float* W1  = (const float*)d_in[2];
    const float* b1  = (const float*)d_in[3];
    const float* W2  = (const float*)d_in[4];
    const float* b2  = (const float*)d_in[5];
    const float* fcW = (const float*)d_in[6];
    const float* fcb = (const float*)d_in[7];
    float* out = (float*)d_out;

    const int n  = in_sizes[0] / FDIM;    // 100000
    const int ne = in_sizes[1] / 2;       // 1600000
    const int* src = ei;
    const int* dst = ei + ne;

    const int gN = (n + 255) / 256;
    const int gE = (ne + 255) / 256;
    const int nbkt = (n + 127) >> 7;      // real bucket count (<= NBKT)
    const int gB = (ne + 8191) / 8192;    // binfill blocks

    size_t need = (size_t)ne * 8 + (size_t)n * FDIM * 2 * 2 + 2 * FDIM * FDIM * 2 +
                  ((size_t)n + 2 * FDIM) * 4 +
                  ((size_t)n + (size_t)(BHB + 2) * NBKT + ne) * 4;

    if (ws_size >= need && nbkt <= NBKT) {
        unsigned long long* ebuf = (unsigned long long*)d_ws;
        _Float16* h    = (_Float16*)(ebuf + ne);
        _Float16* xbuf = h + (size_t)n * FDIM;
        _Float16* w1t  = xbuf + (size_t)n * FDIM;
        _Float16* w2t  = w1t + FDIM * FDIM;
        float* dinv    = (float*)(w2t + FDIM * FDIM);
        float* colsum  = dinv + n;
        float* colmax  = colsum + FDIM;
        int* work      = (int*)(colmax + FDIM);
        int* bucketPart= work + n;
        int* bucketBase= bucketPart + BHB * NBKT;
        int* bucketCur = bucketBase + NBKT;
        int* csr       = bucketCur + NBKT;

        k_zero128<<<1, 256, 0, stream>>>(colsum, colmax);
        k_bhist<<<BHB, 256, 0, stream>>>(dst, bucketPart, ne);
        k_scanB<<<1, NBKT, 0, stream>>>(bucketPart, bucketBase, bucketCur);
        k_binfill<<<gB, 256, 0, stream>>>(src, dst, bucketCur, ebuf, ne);
        k_bucketproc<<<nbkt, 256, 0, stream>>>(ebuf, bucketBase, bucketCur,
                                               work, dinv, csr, n);
        k_transW<<<128, 256, 0, stream>>>(W1, W2, w1t, w2t);

        k_gemm_f16<float><<<512, 256, 0, stream>>>(X, w1t, dinv, h, n);
        k_aggregate<<<2048, 256, 0, stream>>>(work, csr, dinv, h, b1, xbuf, n, ne);
        k_gemm_f16<_Float16><<<512, 256, 0, stream>>>(xbuf, w2t, dinv, h, n);
        k_aggregate<<<2048, 256, 0, stream>>>(work, csr, dinv, h, b2, xbuf, n, ne);

        k_pool_h<<<1024, 256, 0, stream>>>(xbuf, colsum, colmax, n);
        k_fc<<<1, 256, 0, stream>>>(colsum, colmax, fcW, fcb, out, 1.0f / (float)n);
    } else {
        float* h      = (float*)d_ws;
        float* acc    = h + (size_t)n * FDIM;
        float* dinv   = acc + (size_t)n * FDIM;
        float* colsum = dinv + n;
        float* colmax = colsum + FDIM;
        const int gV = (n * 32 + 255) / 256;
        const int gS = (int)(((long long)ne * 64 + 255) / 256);

        k_initF<<<gN, 256, 0, stream>>>(dinv, colsum, colmax, n);
        k_degreeF<<<gE, 256, 0, stream>>>(dst, dinv, ne);
        k_rsqrtF<<<gN, 256, 0, stream>>>(dinv, n);

        k_gemm128F<<<1024, 256, 0, stream>>>(X, W1, h, n);
        k_selfinitF<<<gV, 256, 0, stream>>>(h, dinv, acc, n);
        k_scatterF<<<gS, 256, 0, stream>>>(src, dst, dinv, h, acc, ne);
        k_bias_reluF<<<gV, 256, 0, stream>>>(acc, b1, n);

        k_gemm128F<<<1024, 256, 0, stream>>>(acc, W2, h, n);
        k_selfinitF<<<gV, 256, 0, stream>>>(h, dinv, acc, n);
        k_scatterF<<<gS, 256, 0, stream>>>(src, dst, dinv, h, acc, ne);
        k_bias_reluF<<<gV, 256, 0, stream>>>(acc, b2, n);

        k_pool_f<<<1024, 256, 0, stream>>>(acc, colsum, colmax, n);
        k_fc<<<1, 256, 0, stream>>>(colsum, colmax, fcW, fcb, out, 1.0f / (float)n);
    }
}

// Round 9
// 383.743 us; speedup vs baseline: 2.2935x; 1.0106x over previous
//
#include <hip/hip_runtime.h>
#include <hip/hip_bf16.h>
#include <hip/hip_fp16.h>

static constexpr int FDIM = 128;
static constexpr int NBKT = 1024;       // padded bucket count (bucket = dst>>7)
static constexpr int BHB = 128;         // bhist blocks (partial histograms)

typedef _Float16 h8 __attribute__((ext_vector_type(8)));
typedef _Float16 h2 __attribute__((ext_vector_type(2)));
typedef float v4f __attribute__((ext_vector_type(4)));

// ================= fused prep: bhist | transW | zero =================
// blocks [0,BHB): per-block bucket histogram -> private partials
// blocks [BHB, BHB+128): W1/W2 transpose + fp16 cast
// block BHB+128: zero colsum/colmax

__global__ __launch_bounds__(256) void k_prep(const int* __restrict__ dst,
                                              int* __restrict__ bucketPart,
                                              const float* __restrict__ W1,
                                              const float* __restrict__ W2,
                                              _Float16* __restrict__ T1,
                                              _Float16* __restrict__ T2,
                                              float* __restrict__ colsum,
                                              float* __restrict__ colmax, int ne) {
    const int b = blockIdx.x;
    if (b < BHB) {
        __shared__ int lb[NBKT];
        for (int j = threadIdx.x; j < NBKT; j += 256) lb[j] = 0;
        __syncthreads();
        const int stride = BHB * 256;
        for (int e = b * 256 + threadIdx.x; e < ne; e += stride)
            atomicAdd(&lb[dst[e] >> 7], 1);
        __syncthreads();
        int* mine = bucketPart + b * NBKT;
        for (int j = threadIdx.x; j < NBKT; j += 256) mine[j] = lb[j];
    } else if (b < BHB + 128) {
        int bb = b - BHB;                         // 0..127
        const float* W = (bb < 64) ? W1 : W2;
        _Float16* T = (bb < 64) ? T1 : T2;
        int idx = (bb & 63) * 256 + threadIdx.x;  // 0..16383
        int k = idx >> 7, nn = idx & 127;
        T[nn * FDIM + k] = (_Float16)W[idx];
    } else {
        int i = threadIdx.x;
        if (i < FDIM) { colsum[i] = 0.0f; colmax[i] = 0.0f; }
    }
}

// reduce partials + exclusive scan -> bucketBase, bucketCur
__global__ __launch_bounds__(1024) void k_scanB(const int* __restrict__ bucketPart,
                                                int* __restrict__ bucketBase,
                                                int* __restrict__ bucketCur) {
    __shared__ int tmp[NBKT];
    int t = threadIdx.x;
    int v = 0;
    for (int k = 0; k < BHB; k++) v += bucketPart[k * NBKT + t];
    tmp[t] = v;
    __syncthreads();
    for (int off = 1; off < NBKT; off <<= 1) {
        int u = (t >= off) ? tmp[t - off] : 0;
        __syncthreads();
        tmp[t] += u;
        __syncthreads();
    }
    int excl = tmp[t] - v;
    bucketBase[t] = excl;
    bucketCur[t] = excl;
}

// bin edges into bucket-contiguous ebuf (8B packed), 8192 edges/block:
// LDS histogram -> one global reservation atomic per touched bucket -> scatter
__global__ __launch_bounds__(256) void k_binfill(const int* __restrict__ src,
                                                 const int* __restrict__ dst,
                                                 int* __restrict__ bucketCur,
                                                 unsigned long long* __restrict__ ebuf,
                                                 int ne) {
    __shared__ int lcnt[NBKT];    // phase1: counts, phase3: local cursor
    __shared__ int lbase[NBKT];   // reserved global base per bucket
    const int e0 = blockIdx.x * 8192;
    for (int j = threadIdx.x; j < NBKT; j += 256) lcnt[j] = 0;
    __syncthreads();

    int dcache[32];
#pragma unroll
    for (int i = 0; i < 32; i++) {
        int e = e0 + i * 256 + threadIdx.x;
        int d = (e < ne) ? dst[e] : -1;
        dcache[i] = d;
        if (d >= 0) atomicAdd(&lcnt[d >> 7], 1);
    }
    __syncthreads();

    for (int j = threadIdx.x; j < NBKT; j += 256) {
        int c = lcnt[j];
        lbase[j] = c ? atomicAdd(&bucketCur[j], c) : 0;
        lcnt[j] = 0;      // safe: only this thread touches index j in this phase
    }
    __syncthreads();

#pragma unroll
    for (int i = 0; i < 32; i++) {
        int e = e0 + i * 256 + threadIdx.x;
        if (e < ne) {
            int d = dcache[i];
            int s = src[e];
            int b = d >> 7;
            int lp = atomicAdd(&lcnt[b], 1);
            ebuf[lbase[b] + lp] =
                ((unsigned long long)(unsigned)d << 32) | (unsigned)s;
        }
    }
}

// per bucket: count 128 nodes (LDS), scan (LDS), emit work/dinv, fill csr.
__global__ __launch_bounds__(256) void k_bucketproc(const unsigned long long* __restrict__ ebuf,
                                                    const int* __restrict__ bucketBase,
                                                    const int* __restrict__ bucketEnd,
                                                    int* __restrict__ work,
                                                    float* __restrict__ dinv,
                                                    int* __restrict__ csr, int n) {
    __shared__ int cnt[128];
    __shared__ int scn[128];
    const int b = blockIdx.x;
    const int base = b << 7;
    const int beg = bucketBase[b], end = bucketEnd[b];

    if (threadIdx.x < 128) cnt[threadIdx.x] = 0;
    __syncthreads();
    for (int i = beg + threadIdx.x; i < end; i += 256) {
        int d = (int)(ebuf[i] >> 32);
        atomicAdd(&cnt[d & 127], 1);
    }
    __syncthreads();

    int v = 0;
    if (threadIdx.x < 128) { v = cnt[threadIdx.x]; scn[threadIdx.x] = v; }
    __syncthreads();
    for (int off = 1; off < 128; off <<= 1) {
        int t = 0;
        if (threadIdx.x < 128 && threadIdx.x >= off) t = scn[threadIdx.x - off];
        __syncthreads();
        if (threadIdx.x < 128) scn[threadIdx.x] += t;
        __syncthreads();
    }
    if (threadIdx.x < 128) {
        int node = base + threadIdx.x;
        if (node < n) {
            int w = beg + scn[threadIdx.x] - v;      // exclusive within bucket
            work[node] = w;
            dinv[node] = 1.0f / sqrtf(1.0f + (float)v);
            cnt[threadIdx.x] = w;                    // reuse as cursor
        }
    }
    __syncthreads();

    for (int i = beg + threadIdx.x; i < end; i += 256) {
        unsigned long long p = ebuf[i];
        int d = (int)(p >> 32);
        int s = (int)(p & 0xffffffffu);
        int pos = atomicAdd(&cnt[d & 127], 1);
        csr[pos] = s;
    }
}

// ---------- MFMA GEMM: H(fp16) = dinv[r] * (X @ W)  (M x 128 x 128) ----------

template <typename T>
__global__ __launch_bounds__(256) void k_gemm_f16(const T* __restrict__ X,
                                                  const _Float16* __restrict__ WT,
                                                  const float* __restrict__ dinv,
                                                  _Float16* __restrict__ H, int n) {
    __shared__ _Float16 sA[FDIM * FDIM];   // 32 KB
    __shared__ _Float16 sB[FDIM * FDIM];   // 32 KB
    const int t = threadIdx.x;
    const int lane = t & 63;
    const int w = t >> 6;
    const int rowhalf = w >> 1, colhalf = w & 1;

    for (int i = 0; i < 8; i++) {          // stage W^T once
        int f = i * 256 + t;
        int nn = f >> 4, g = f & 15;
        ((float4*)sB)[nn * 16 + ((g ^ nn) & 15)] = ((const float4*)WT)[f];
    }

    const int ntiles = (n + 127) >> 7;
    for (int tile = blockIdx.x; tile < ntiles; tile += gridDim.x) {
        const int R0 = tile << 7;
        __syncthreads();                    // frag readers done / sB staged
        for (int i = 0; i < 8; i++) {
            int f = i * 256 + t;
            int row = f >> 4, g = f & 15;
            int gr = min(R0 + row, n - 1);
            h8 val;
            if constexpr (sizeof(T) == 4) {
                const float4* xp = (const float4*)(X + (size_t)gr * FDIM + g * 8);
                float4 u0 = xp[0], u1 = xp[1];
                val[0] = (_Float16)u0.x; val[1] = (_Float16)u0.y;
                val[2] = (_Float16)u0.z; val[3] = (_Float16)u0.w;
                val[4] = (_Float16)u1.x; val[5] = (_Float16)u1.y;
                val[6] = (_Float16)u1.z; val[7] = (_Float16)u1.w;
            } else {
                val = ((const h8*)(X + (size_t)gr * FDIM))[g];
            }
            ((h8*)sA)[row * 16 + ((g ^ row) & 15)] = val;
        }
        __syncthreads();

        v4f acc[4][4];
#pragma unroll
        for (int rt = 0; rt < 4; rt++)
#pragma unroll
            for (int ct = 0; ct < 4; ct++)
                acc[rt][ct] = (v4f){0.f, 0.f, 0.f, 0.f};

#pragma unroll
        for (int s = 0; s < 4; s++) {
            const int g0 = s * 4 + (lane >> 4);
            h8 af[4], bf[4];
#pragma unroll
            for (int rt = 0; rt < 4; rt++) {
                int row = rowhalf * 64 + rt * 16 + (lane & 15);
                af[rt] = ((const h8*)sA)[row * 16 + ((g0 ^ row) & 15)];
            }
#pragma unroll
            for (int ct = 0; ct < 4; ct++) {
                int nn = colhalf * 64 + ct * 16 + (lane & 15);
                bf[ct] = ((const h8*)sB)[nn * 16 + ((g0 ^ nn) & 15)];
            }
#pragma unroll
            for (int rt = 0; rt < 4; rt++)
#pragma unroll
                for (int ct = 0; ct < 4; ct++)
                    acc[rt][ct] = __builtin_amdgcn_mfma_f32_16x16x32_f16(
                        af[rt], bf[ct], acc[rt][ct], 0, 0, 0);
        }

        // epilogue: C/D layout col = lane&15, row = (lane>>4)*4 + reg; fuse dinv
        const int rb = R0 + rowhalf * 64 + (lane >> 4) * 4;
        const int cb = colhalf * 64 + (lane & 15);
#pragma unroll
        for (int rt = 0; rt < 4; rt++)
#pragma unroll
            for (int reg = 0; reg < 4; reg++) {
                int grow = rb + rt * 16 + reg;
                if (grow < n) {
                    float d = dinv[grow];
                    _Float16* hp = H + (size_t)grow * FDIM + cb;
#pragma unroll
                    for (int ct = 0; ct < 4; ct++)
                        hp[ct * 16] = (_Float16)(acc[rt][ct][reg] * d);
                }
            }
    }
}

// ---------- gather aggregate (fp16 pre-scaled messages, fp32 accumulate) ----------
// hs[r] = dinv[r]*(XW)[r];  out[d] = relu(dinv[d]*(hs[d] + sum_s hs[s]) + b).
// 8-wide unrolled gather: 8 independent 256B loads in flight per wave.

__global__ __launch_bounds__(256) void k_aggregate(const int* __restrict__ work,
                                                   const int* __restrict__ csr,
                                                   const float* __restrict__ dinv,
                                                   const _Float16* __restrict__ hs,
                                                   const float* __restrict__ bias,
                                                   _Float16* __restrict__ out,
                                                   int n, int ne) {
    const int lane = threadIdx.x & 63;
    const int nwaves = gridDim.x * 4;
    int wid = (blockIdx.x * 256 + threadIdx.x) >> 6;
    const h2* hs2 = (const h2*)hs;
    const float2 bb = ((const float2*)bias)[lane];

    for (int node = wid; node < n; node += nwaves) {
        int beg = work[node];
        int end = (node + 1 < n) ? work[node + 1] : ne;
        float dd = dinv[node];
        h2 hv = hs2[(size_t)node * 64 + lane];
        float ax = (float)hv[0];
        float ay = (float)hv[1];
        for (int chunk = beg; chunk < end; chunk += 64) {
            int m = end - chunk; if (m > 64) m = 64;
            int myidx = (lane < m) ? csr[chunk + lane] : 0;
            int j = 0;
            for (; j + 8 <= m; j += 8) {
                int s0 = __shfl(myidx, j + 0);
                int s1 = __shfl(myidx, j + 1);
                int s2 = __shfl(myidx, j + 2);
                int s3 = __shfl(myidx, j + 3);
                int s4 = __shfl(myidx, j + 4);
                int s5 = __shfl(myidx, j + 5);
                int s6 = __shfl(myidx, j + 6);
                int s7 = __shfl(myidx, j + 7);
                h2 v0 = hs2[(size_t)s0 * 64 + lane];
                h2 v1 = hs2[(size_t)s1 * 64 + lane];
                h2 v2 = hs2[(size_t)s2 * 64 + lane];
                h2 v3 = hs2[(size_t)s3 * 64 + lane];
                h2 v4 = hs2[(size_t)s4 * 64 + lane];
                h2 v5 = hs2[(size_t)s5 * 64 + lane];
                h2 v6 = hs2[(size_t)s6 * 64 + lane];
                h2 v7 = hs2[(size_t)s7 * 64 + lane];
                ax += (float)v0[0] + (float)v1[0] + (float)v2[0] + (float)v3[0]
                    + (float)v4[0] + (float)v5[0] + (float)v6[0] + (float)v7[0];
                ay += (float)v0[1] + (float)v1[1] + (float)v2[1] + (float)v3[1]
                    + (float)v4[1] + (float)v5[1] + (float)v6[1] + (float)v7[1];
            }
            for (; j < m; j++) {
                int s = __shfl(myidx, j);
                h2 v = hs2[(size_t)s * 64 + lane];
                ax += (float)v[0];
                ay += (float)v[1];
            }
        }
        float ox = fmaxf(ax * dd + bb.x, 0.f);
        float oy = fmaxf(ay * dd + bb.y, 0.f);
        h2 o; o[0] = (_Float16)ox; o[1] = (_Float16)oy;
        ((h2*)out)[(size_t)node * 64 + lane] = o;
    }
}

// ---------- pools ----------

__global__ __launch_bounds__(256) void k_pool_h(const _Float16* __restrict__ X,
                                                float* __restrict__ colsum,
                                                float* __restrict__ colmax, int n) {
    __shared__ float ls[256], lm[256];
    int c = threadIdx.x & 127;
    int grp = threadIdx.x >> 7;
    float s = 0.f, m = 0.f;
    for (int r = blockIdx.x * 2 + grp; r < n; r += gridDim.x * 2) {
        float v = (float)X[(size_t)r * FDIM + c];
        s += v;
        m = fmaxf(m, v);
    }
    ls[threadIdx.x] = s;
    lm[threadIdx.x] = m;
    __syncthreads();
    if (threadIdx.x < 128) {
        s = ls[threadIdx.x] + ls[threadIdx.x + 128];
        m = fmaxf(lm[threadIdx.x], lm[threadIdx.x + 128]);
        unsafeAtomicAdd(&colsum[c], s);
        atomicMax((int*)colmax + c, __float_as_int(m));
    }
}

__global__ __launch_bounds__(256) void k_pool_f(const float* __restrict__ X,
                                                float* __restrict__ colsum,
                                                float* __restrict__ colmax, int n) {
    __shared__ float ls[256], lm[256];
    int c = threadIdx.x & 127;
    int grp = threadIdx.x >> 7;
    float s = 0.f, m = 0.f;
    for (int r = blockIdx.x * 2 + grp; r < n; r += gridDim.x * 2) {
        float v = X[(size_t)r * FDIM + c];
        s += v;
        m = fmaxf(m, v);
    }
    ls[threadIdx.x] = s;
    lm[threadIdx.x] = m;
    __syncthreads();
    if (threadIdx.x < 128) {
        s = ls[threadIdx.x] + ls[threadIdx.x + 128];
        m = fmaxf(lm[threadIdx.x], lm[threadIdx.x + 128]);
        unsafeAtomicAdd(&colsum[c], s);
        atomicMax((int*)colmax + c, __float_as_int(m));
    }
}

__global__ __launch_bounds__(256) void k_fc(const float* __restrict__ colsum,
                                            const float* __restrict__ colmax,
                                            const float* __restrict__ fcW,
                                            const float* __restrict__ fcb,
                                            float* __restrict__ out, float invN) {
    int o = threadIdx.x;
    float acc = fcb[o];
#pragma unroll 4
    for (int k = 0; k < FDIM; k++)
        acc += colsum[k] * invN * fcW[k * 256 + o];
#pragma unroll 4
    for (int k = 0; k < FDIM; k++)
        acc += colmax[k] * fcW[(FDIM + k) * 256 + o];
    out[o] = acc;
}

// ================= fallback (round-1 atomic scatter, fp32) =================

__global__ __launch_bounds__(256) void k_initF(float* deg, float* cs, float* cm, int n) {
    int i = blockIdx.x * 256 + threadIdx.x;
    if (i < n) deg[i] = 1.0f;
    if (i < FDIM) { cs[i] = 0.0f; cm[i] = 0.0f; }
}
__global__ __launch_bounds__(256) void k_degreeF(const int* dst, float* deg, int ne) {
    int i = blockIdx.x * 256 + threadIdx.x;
    if (i < ne) unsafeAtomicAdd(&deg[dst[i]], 1.0f);
}
__global__ __launch_bounds__(256) void k_rsqrtF(float* deg, int n) {
    int i = blockIdx.x * 256 + threadIdx.x;
    if (i < n) deg[i] = 1.0f / sqrtf(deg[i]);
}
__global__ __launch_bounds__(256) void k_selfinitF(const float* H, const float* dinv,
                                                   float* acc, int n) {
    int i = blockIdx.x * 256 + threadIdx.x;
    if (i >= n * 32) return;
    int row = i >> 5;
    float s = dinv[row]; s *= s;
    float4 v = ((const float4*)H)[i];
    v.x *= s; v.y *= s; v.z *= s; v.w *= s;
    ((float4*)acc)[i] = v;
}
__global__ __launch_bounds__(256) void k_scatterF(const int* src, const int* dst,
                                                  const float* dinv, const float* H,
                                                  float* acc, int ne) {
    int e = (blockIdx.x * 256 + threadIdx.x) >> 6;
    if (e >= ne) return;
    int lane = threadIdx.x & 63;
    int s = src[e], d = dst[e];
    float w = dinv[s] * dinv[d];
    float2 v = ((const float2*)(H + (size_t)s * FDIM))[lane];
    float* ap = acc + (size_t)d * FDIM + lane * 2;
    unsafeAtomicAdd(ap, v.x * w);
    unsafeAtomicAdd(ap + 1, v.y * w);
}
__global__ __launch_bounds__(256) void k_bias_reluF(float* acc, const float* b, int n) {
    int i = blockIdx.x * 256 + threadIdx.x;
    if (i >= n * 32) return;
    float4 bb = ((const float4*)b)[i & 31];
    float4 v = ((float4*)acc)[i];
    v.x = fmaxf(v.x + bb.x, 0.f);
    v.y = fmaxf(v.y + bb.y, 0.f);
    v.z = fmaxf(v.z + bb.z, 0.f);
    v.w = fmaxf(v.w + bb.w, 0.f);
    ((float4*)acc)[i] = v;
}
__global__ __launch_bounds__(256) void k_gemm128F(const float* X, const float* W,
                                                   float* H, int n) {
    __shared__ float sW[FDIM * FDIM];
    for (int i = threadIdx.x; i < FDIM * FDIM / 4; i += 256)
        ((float4*)sW)[i] = ((const float4*)W)[i];
    __syncthreads();
    const int c = threadIdx.x & 127;
    const int half = threadIdx.x >> 7;
    for (int base = blockIdx.x * 8; base < n; base += gridDim.x * 8) {
        const int r0 = base + half * 4;
        const float* xp0 = X + (size_t)min(r0 + 0, n - 1) * FDIM;
        const float* xp1 = X + (size_t)min(r0 + 1, n - 1) * FDIM;
        const float* xp2 = X + (size_t)min(r0 + 2, n - 1) * FDIM;
        const float* xp3 = X + (size_t)min(r0 + 3, n - 1) * FDIM;
        float a0 = 0.f, a1 = 0.f, a2 = 0.f, a3 = 0.f;
#pragma unroll 8
        for (int k = 0; k < FDIM; k += 4) {
            float w0 = sW[(k + 0) * FDIM + c];
            float w1 = sW[(k + 1) * FDIM + c];
            float w2 = sW[(k + 2) * FDIM + c];
            float w3 = sW[(k + 3) * FDIM + c];
            float4 x0 = *(const float4*)(xp0 + k);
            float4 x1 = *(const float4*)(xp1 + k);
            float4 x2 = *(const float4*)(xp2 + k);
            float4 x3 = *(const float4*)(xp3 + k);
            a0 += x0.x * w0 + x0.y * w1 + x0.z * w2 + x0.w * w3;
            a1 += x1.x * w0 + x1.y * w1 + x1.z * w2 + x1.w * w3;
            a2 += x2.x * w0 + x2.y * w1 + x2.z * w2 + x2.w * w3;
            a3 += x3.x * w0 + x3.y * w1 + x3.z * w2 + x3.w * w3;
        }
        if (r0 + 0 < n) H[(size_t)(r0 + 0) * FDIM + c] = a0;
        if (r0 + 1 < n) H[(size_t)(r0 + 1) * FDIM + c] = a1;
        if (r0 + 2 < n) H[(size_t)(r0 + 2) * FDIM + c] = a2;
        if (r0 + 3 < n) H[(size_t)(r0 + 3) * FDIM + c] = a3;
    }
}

// ================= launch =================

extern "C" void kernel_launch(void* const* d_in, const int* in_sizes, int n_in,
                              void* d_out, int out_size, void* d_ws, size_t ws_size,
                              hipStream_t stream) {
    const float* X   = (const float*)d_in[0];
    const int*   ei  = (const int*)d_in[1];
    const float* W1  = (const float*)d_in[2];
    const float* b1  = (const float*)d_in[3];
    const float* W2  = (const float*)d_in[4];
    const float* b2  = (const float*)d_in[5];
    const float* fcW = (const float*)d_in[6];
    const float* fcb = (const float*)d_in[7];
    float* out = (float*)d_out;

    const int n  = in_sizes[0] / FDIM;    // 100000
    const int ne = in_sizes[1] / 2;       // 1600000
    const int* src = ei;
    const int* dst = ei + ne;

    const int gN = (n + 255) / 256;
    const int gE = (ne + 255) / 256;
    const int nbkt = (n + 127) >> 7;      // real bucket count (<= NBKT)
    const int gB = (ne + 8191) / 8192;    // binfill blocks

    size_t need = (size_t)ne * 8 + (size_t)n * FDIM * 2 * 2 + 2 * FDIM * FDIM * 2 +
                  ((size_t)n + 2 * FDIM) * 4 +
                  ((size_t)n + (size_t)(BHB + 2) * NBKT + ne) * 4;

    if (ws_size >= need && nbkt <= NBKT) {
        unsigned long long* ebuf = (unsigned long long*)d_ws;
        _Float16* h    = (_Float16*)(ebuf + ne);
        _Float16* xbuf = h + (size_t)n * FDIM;
        _Float16* w1t  = xbuf + (size_t)n * FDIM;
        _Float16* w2t  = w1t + FDIM * FDIM;
        float* dinv    = (float*)(w2t + FDIM * FDIM);
        float* colsum  = dinv + n;
        float* colmax  = colsum + FDIM;
        int* work      = (int*)(colmax + FDIM);
        int* bucketPart= work + n;
        int* bucketBase= bucketPart + BHB * NBKT;
        int* bucketCur = bucketBase + NBKT;
        int* csr       = bucketCur + NBKT;

        k_prep<<<BHB + 128 + 1, 256, 0, stream>>>(dst, bucketPart, W1, W2,
                                                  w1t, w2t, colsum, colmax, ne);
        k_scanB<<<1, NBKT, 0, stream>>>(bucketPart, bucketBase, bucketCur);
        k_binfill<<<gB, 256, 0, stream>>>(src, dst, bucketCur, ebuf, ne);
        k_bucketproc<<<nbkt, 256, 0, stream>>>(ebuf, bucketBase, bucketCur,
                                               work, dinv, csr, n);

        k_gemm_f16<float><<<512, 256, 0, stream>>>(X, w1t, dinv, h, n);
        k_aggregate<<<2048, 256, 0, stream>>>(work, csr, dinv, h, b1, xbuf, n, ne);
        k_gemm_f16<_Float16><<<512, 256, 0, stream>>>(xbuf, w2t, dinv, h, n);
        k_aggregate<<<2048, 256, 0, stream>>>(work, csr, dinv, h, b2, xbuf, n, ne);

        k_pool_h<<<1024, 256, 0, stream>>>(xbuf, colsum, colmax, n);
        k_fc<<<1, 256, 0, stream>>>(colsum, colmax, fcW, fcb, out, 1.0f / (float)n);
    } else {
        float* h      = (float*)d_ws;
        float* acc    = h + (size_t)n * FDIM;
        float* dinv   = acc + (size_t)n * FDIM;
        float* colsum = dinv + n;
        float* colmax = colsum + FDIM;
        const int gV = (n * 32 + 255) / 256;
        const int gS = (int)(((long long)ne * 64 + 255) / 256);

        k_initF<<<gN, 256, 0, stream>>>(dinv, colsum, colmax, n);
        k_degreeF<<<gE, 256, 0, stream>>>(dst, dinv, ne);
        k_rsqrtF<<<gN, 256, 0, stream>>>(dinv, n);

        k_gemm128F<<<1024, 256, 0, stream>>>(X, W1, h, n);
        k_selfinitF<<<gV, 256, 0, stream>>>(h, dinv, acc, n);
        k_scatterF<<<gS, 256, 0, stream>>>(src, dst, dinv, h, acc, ne);
        k_bias_reluF<<<gV, 256, 0, stream>>>(acc, b1, n);

        k_gemm128F<<<1024, 256, 0, stream>>>(acc, W2, h, n);
        k_selfinitF<<<gV, 256, 0, stream>>>(h, dinv, acc, n);
        k_scatterF<<<gS, 256, 0, stream>>>(src, dst, dinv, h, acc, ne);
        k_bias_reluF<<<gV, 256, 0, stream>>>(acc, b2, n);

        k_pool_f<<<1024, 256, 0, stream>>>(acc, colsum, colmax, n);
        k_fc<<<1, 256, 0, stream>>>(colsum, colmax, fcW, fcb, out, 1.0f / (float)n);
    }
}